// Round 5
// baseline (225.642 us; speedup 1.0000x reference)
//
#include <hip/hip_runtime.h>

// HGCN on MI355X. logmap0(expmap0(v)) == v here, so the model reduces to:
//   t1 = sigmoid(segmean(feat@W1+b1)); t2 = sigmoid(segmean(t1@W2+b2))
//   out = relu(t2@W3+b3)@W4 + b4     (segmean commutes with the linear map;
//   deg-0 nodes: segmean = 0 -> value 0.5 exactly, handled via dz check)
// R1-R13: see session journal (atomic wall -> CSR; coarse buckets; bf16
//   gather rows; frag-packed weight image; wave-local zero-barrier MLP).
// R14: baseline re-anchor, 229.4us. Gathers latency-bound (occ 31%).
// R15: FAILED (1356us). LDS float atomicAdd = CAS loop, not ds_add_f32.
// R16: FAILED (240us). 1563 fine buckets -> 10.5B arena runs -> write-amp;
//   per-layer in-block sort costs 2x. Partition needs COARSE buckets.
// R17: WIN (219us). csr_fine @1024thr; gathers 128thr/32-row. aggep3 59->48.
//   Occupancy STILL 30% => waves serially latency-bound (~19us block life
//   for ~512 edges = ~6.5 batches x ~600cy RTT per pass pair).
// R18: (a) gather pipeline depth 8->16 loads in flight (halves serial
//   batches; VGPR ~100 still 4 waves/SIMD); (b) part_prep partition at
//   512 threads (12 waves/CU vs 6) + wave-shuffle scan (3 barriers vs 16),
//   EPB unchanged (84B arena runs preserved). Predicted ~180us.

constexpr int CSHIFT = 9;               // 512 nodes per coarse bucket
constexpr int CNODES = 1 << CSHIFT;
constexpr int EPB    = 4096;            // edges per partition block
constexpr int PTHR   = 512;             // partition block threads (R18)
constexpr int EPT    = EPB / PTHR;      // 8 edges/thread
constexpr int CAP    = 16384;           // arena capacity per bucket (mean 8163)

// frag-packed bf16 weight image (shorts). Fragment = 16 lanes x 8 shorts =
// 128 shorts; flat idx = (((c*KK + kk)*4 + quad)*16 + m)*8 + j.
constexpr int W1F_OFF = 0;              // 4x2x4 frags  = 4096 shorts
constexpr int W2F_OFF = 4096;           // 4096
constexpr int W3F_OFF = 8192;           // 8x2x4 frags  = 8192
constexpr int W4F_OFF = 16384;          // 3x4x4 frags  = 6144 (cols padded 48)
constexpr int WIMG_TOT = 22528;

typedef __attribute__((ext_vector_type(8))) short short8;   // 8 bf16
typedef __attribute__((ext_vector_type(4))) float floatx4;  // MFMA acc

__device__ __forceinline__ float sigmoidf(float x) {
    return 1.0f / (1.0f + __expf(-x));
}
__device__ __forceinline__ unsigned short f2bf(float f) {   // RNE f32->bf16
    unsigned int u = __float_as_uint(f);
    u = (u + 0x7FFFu + ((u >> 16) & 1u)) >> 16;
    return (unsigned short)u;
}

// ---------------- CSR partition + one-time prep (merged launch) ------------
// Blocks [0,gP): radix-partition edges into per-bucket arena regions
//   (512 threads = 12 waves/CU at 1.5 blocks/CU; shuffle scan, 5 barriers).
// Blocks [gP,..): feat fp32->bf16 cast + frag-packed weight image build.
__global__ __launch_bounds__(512) void part_prep_k(
    const int* __restrict__ src, const int* __restrict__ dst,
    int* __restrict__ ccur, int* __restrict__ arena, int E, int NBUCK, int gP,
    const float* __restrict__ feat, unsigned short* __restrict__ featbf,
    const float* __restrict__ W1, const float* __restrict__ W2,
    const float* __restrict__ W3, const float* __restrict__ W4,
    unsigned short* __restrict__ img, int n8)
{
    __shared__ int  hist[256];
    __shared__ int  exoff[256];
    __shared__ int  lcur[256];
    __shared__ int  gbase[256];
    __shared__ int  wsum[4];
    __shared__ int  stage[EPB];
    __shared__ unsigned char stageB[EPB];

    const int tid = threadIdx.x;

    if ((int)blockIdx.x >= gP) {
        // ---- prep path ----
        int i = ((int)blockIdx.x - gP) * PTHR + tid;
        if (i < n8) {
            const float4* p = (const float4*)feat + (size_t)i * 2;
            float4 a = p[0], b = p[1];
            uint4 o;
            o.x = (unsigned)f2bf(a.x) | ((unsigned)f2bf(a.y) << 16);
            o.y = (unsigned)f2bf(a.z) | ((unsigned)f2bf(a.w) << 16);
            o.z = (unsigned)f2bf(b.x) | ((unsigned)f2bf(b.y) << 16);
            o.w = (unsigned)f2bf(b.z) | ((unsigned)f2bf(b.w) << 16);
            ((uint4*)featbf)[i] = o;
            return;
        }
        int t = i - n8;
        if (t >= WIMG_TOT) return;
        float v = 0.f;
        int s = t;
        if (s < W2F_OFF) {                       // W1 [64x64]
            int j = s & 7, m = (s >> 3) & 15, q = (s >> 7) & 3, kk = (s >> 9) & 1, c = s >> 10;
            v = W1[(kk * 32 + q * 8 + j) * 64 + c * 16 + m];
        } else if (s < W3F_OFF) {                // W2 [64x64]
            s -= W2F_OFF;
            int j = s & 7, m = (s >> 3) & 15, q = (s >> 7) & 3, kk = (s >> 9) & 1, c = s >> 10;
            v = W2[(kk * 32 + q * 8 + j) * 64 + c * 16 + m];
        } else if (s < W4F_OFF) {                // W3 [64x128]
            s -= W3F_OFF;
            int j = s & 7, m = (s >> 3) & 15, q = (s >> 7) & 3, kk = (s >> 9) & 1, c = s >> 10;
            v = W3[(kk * 32 + q * 8 + j) * 128 + c * 16 + m];
        } else {                                 // W4 [128x40], cols padded 48
            s -= W4F_OFF;
            int j = s & 7, m = (s >> 3) & 15, q = (s >> 7) & 3, kk = (s >> 9) & 3, c = s >> 11;
            int n = c * 16 + m;
            if (n < 40) v = W4[(kk * 32 + q * 8 + j) * 40 + n];
        }
        img[t] = f2bf(v);
        return;
    }

    // ---- partition path (512 threads) ----
    const int e0  = blockIdx.x * EPB;
    const int ec  = min(EPB, E - e0);
    const int lane = tid & 63, wid = tid >> 6;

    int pk[EPT], bk[EPT];
    if (tid < 256) hist[tid] = 0;
    __syncthreads();
    #pragma unroll
    for (int j = 0; j < EPT; j++) {
        int idx = tid + j * PTHR;
        if (idx < ec) {
            int s = src[e0 + idx];
            int d = dst[e0 + idx];
            bk[j] = d >> CSHIFT;
            pk[j] = s | ((d & (CNODES - 1)) << 17);
            atomicAdd(&hist[bk[j]], 1);
        } else bk[j] = -1;
    }
    __syncthreads();
    // shuffle scan of hist[256] on waves 0-3 (wave-uniform branch)
    int h = 0, v = 0;
    if (tid < 256) {
        h = hist[tid];
        v = h;
        #pragma unroll
        for (int d = 1; d < 64; d <<= 1) {
            int t = __shfl_up(v, d);
            if (lane >= d) v += t;
        }
        if (lane == 63) wsum[wid] = v;
    }
    __syncthreads();
    if (tid == 0) {
        int s = 0;
        #pragma unroll
        for (int k = 0; k < 4; k++) { int t = wsum[k]; wsum[k] = s; s += t; }
    }
    __syncthreads();
    if (tid < 256) {
        int ex = wsum[wid] + v - h;
        int gb = 0;
        if (tid < NBUCK && h > 0) gb = atomicAdd(ccur + tid, h);
        exoff[tid] = ex;
        lcur[tid]  = ex;
        gbase[tid] = gb;
    }
    __syncthreads();
    #pragma unroll
    for (int j = 0; j < EPT; j++) {
        if (bk[j] >= 0) {
            int l = atomicAdd(&lcur[bk[j]], 1);
            stage[l]  = pk[j];
            stageB[l] = (unsigned char)bk[j];
        }
    }
    __syncthreads();
    for (int i = tid; i < ec; i += PTHR) {
        int b = stageB[i];
        arena[(size_t)b * CAP + gbase[b] + (i - exoff[b])] = stage[i];
    }
}

// One 1024-thread block per coarse bucket (R17): 16 waves hide the arena
// read + LDS-atomic latency; inline scan of bucket counts -> cbeg; LDS
// counting sort over 512 nodes -> off/ssrc.
__global__ __launch_bounds__(1024) void csr_fine(const int* __restrict__ arena,
                                                 const int* __restrict__ ccur,
                                                 int* __restrict__ off,
                                                 int* __restrict__ ssrc,
                                                 int N, int E, int NBUCK) {
    __shared__ int part[256];
    __shared__ int cnt[CNODES];
    __shared__ int cur[CNODES];
    __shared__ int wpre[8];
    const int b = blockIdx.x;
    const int node0 = b << CSHIFT;
    const int tid = threadIdx.x;
    const int lane = tid & 63, wid = tid >> 6;

    // exclusive prefix of ccur over buckets -> cbeg (threads 0-255 work,
    // ALL threads hit every barrier)
    if (tid < 256) part[tid] = (tid < NBUCK) ? ccur[tid] : 0;
    __syncthreads();
    for (int d = 1; d < 256; d <<= 1) {
        int v = 0;
        if (tid < 256 && tid >= d) v = part[tid - d];
        __syncthreads();
        if (tid < 256 && tid >= d) part[tid] += v;
        __syncthreads();
    }
    const int cbeg = (b > 0) ? part[b - 1] : 0;
    const int ec   = min(ccur[b], CAP);
    if (b == 0 && tid == 0) off[N] = E;

    if (tid < CNODES) cnt[tid] = 0;
    __syncthreads();
    const int* pe = arena + (size_t)b * CAP;
    for (int i = tid; i < ec; i += 1024)
        atomicAdd(&cnt[(pe[i] >> 17) & (CNODES - 1)], 1);
    __syncthreads();

    // hierarchical scan of cnt[512]: shuffle within 8 waves + serial wave scan
    int c = (tid < CNODES) ? cnt[tid] : 0;
    int v = c;
    #pragma unroll
    for (int d = 1; d < 64; d <<= 1) {
        int t = __shfl_up(v, d);
        if (lane >= d) v += t;
    }
    if (tid < CNODES && lane == 63) wpre[wid] = v;
    __syncthreads();
    if (tid == 0) {
        int s = 0;
        #pragma unroll
        for (int k = 0; k < CNODES / 64; k++) { int t = wpre[k]; wpre[k] = s; s += t; }
    }
    __syncthreads();
    if (tid < CNODES) {
        int ex = wpre[wid] + v - c;              // exclusive prefix in bucket
        cur[tid] = ex;
        int node = node0 + tid;
        if (node < N) off[node] = cbeg + ex;
    }
    __syncthreads();
    for (int i = tid; i < ec; i += 1024) {
        int p = pe[i];
        int pos = cbeg + atomicAdd(&cur[(p >> 17) & (CNODES - 1)], 1);
        ssrc[pos] = p & 0x1FFFF;
    }
}

// ---------------- wave-local gather: mean of h[src] rows into LDS tile -----
// Wave w gathers ITS OWN rows w*16..w*16+15 (2 passes x 8 rows x 8 lanes).
// All later reads of Agg by wave w hit only these rows -> no barrier needed.
// R18: 16 loads in flight per lane (halves serial latency batches).
#define ACC8(v)                                    \
    acc[0] += __uint_as_float((v).x << 16);        \
    acc[1] += __uint_as_float((v).x & 0xFFFF0000u);\
    acc[2] += __uint_as_float((v).y << 16);        \
    acc[3] += __uint_as_float((v).y & 0xFFFF0000u);\
    acc[4] += __uint_as_float((v).z << 16);        \
    acc[5] += __uint_as_float((v).z & 0xFFFF0000u);\
    acc[6] += __uint_as_float((v).w << 16);        \
    acc[7] += __uint_as_float((v).w & 0xFFFF0000u);

__device__ __forceinline__ void gather_tile_wave(
    const unsigned short* __restrict__ h, const int* __restrict__ off,
    const int* __restrict__ ssrc, unsigned short* Agg, int rowB, int N,
    int w, int lane)
{
    #pragma unroll
    for (int pass = 0; pass < 2; pass++) {
        int rl = w * 16 + pass * 8 + (lane >> 3);
        int g  = rowB + rl;
        int q  = (lane & 7) * 8;
        uint4 p = make_uint4(0u, 0u, 0u, 0u);
        if (g < N) {
            int beg = off[g], end = off[g + 1];
            float acc[8] = {0.f, 0.f, 0.f, 0.f, 0.f, 0.f, 0.f, 0.f};
            int i = beg;
            for (; i + 16 <= end; i += 16) {     // 16 loads in flight / lane
                int s0 = ssrc[i],      s1 = ssrc[i + 1];
                int s2 = ssrc[i + 2],  s3 = ssrc[i + 3];
                int s4 = ssrc[i + 4],  s5 = ssrc[i + 5];
                int s6 = ssrc[i + 6],  s7 = ssrc[i + 7];
                int s8 = ssrc[i + 8],  s9 = ssrc[i + 9];
                int sa = ssrc[i + 10], sb = ssrc[i + 11];
                int sc = ssrc[i + 12], sd = ssrc[i + 13];
                int se = ssrc[i + 14], sf = ssrc[i + 15];
                uint4 v0 = *(const uint4*)(h + (size_t)s0 * 64 + q);
                uint4 v1 = *(const uint4*)(h + (size_t)s1 * 64 + q);
                uint4 v2 = *(const uint4*)(h + (size_t)s2 * 64 + q);
                uint4 v3 = *(const uint4*)(h + (size_t)s3 * 64 + q);
                uint4 v4 = *(const uint4*)(h + (size_t)s4 * 64 + q);
                uint4 v5 = *(const uint4*)(h + (size_t)s5 * 64 + q);
                uint4 v6 = *(const uint4*)(h + (size_t)s6 * 64 + q);
                uint4 v7 = *(const uint4*)(h + (size_t)s7 * 64 + q);
                uint4 v8 = *(const uint4*)(h + (size_t)s8 * 64 + q);
                uint4 v9 = *(const uint4*)(h + (size_t)s9 * 64 + q);
                uint4 va = *(const uint4*)(h + (size_t)sa * 64 + q);
                uint4 vb = *(const uint4*)(h + (size_t)sb * 64 + q);
                uint4 vc = *(const uint4*)(h + (size_t)sc * 64 + q);
                uint4 vd = *(const uint4*)(h + (size_t)sd * 64 + q);
                uint4 ve = *(const uint4*)(h + (size_t)se * 64 + q);
                uint4 vf = *(const uint4*)(h + (size_t)sf * 64 + q);
                ACC8(v0); ACC8(v1); ACC8(v2); ACC8(v3);
                ACC8(v4); ACC8(v5); ACC8(v6); ACC8(v7);
                ACC8(v8); ACC8(v9); ACC8(va); ACC8(vb);
                ACC8(vc); ACC8(vd); ACC8(ve); ACC8(vf);
            }
            for (; i + 4 <= end; i += 4) {
                int s0 = ssrc[i],     s1 = ssrc[i + 1];
                int s2 = ssrc[i + 2], s3 = ssrc[i + 3];
                uint4 v0 = *(const uint4*)(h + (size_t)s0 * 64 + q);
                uint4 v1 = *(const uint4*)(h + (size_t)s1 * 64 + q);
                uint4 v2 = *(const uint4*)(h + (size_t)s2 * 64 + q);
                uint4 v3 = *(const uint4*)(h + (size_t)s3 * 64 + q);
                ACC8(v0); ACC8(v1); ACC8(v2); ACC8(v3);
            }
            for (; i < end; i++) {
                uint4 v = *(const uint4*)(h + (size_t)ssrc[i] * 64 + q);
                ACC8(v);
            }
            // v_rcp_f32: 2^-22 rel err, absorbed by the bf16 round
            float inv = __builtin_amdgcn_rcpf((float)max(end - beg, 1));
            p.x = (unsigned)f2bf(acc[0]*inv) | ((unsigned)f2bf(acc[1]*inv) << 16);
            p.y = (unsigned)f2bf(acc[2]*inv) | ((unsigned)f2bf(acc[3]*inv) << 16);
            p.z = (unsigned)f2bf(acc[4]*inv) | ((unsigned)f2bf(acc[5]*inv) << 16);
            p.w = (unsigned)f2bf(acc[6]*inv) | ((unsigned)f2bf(acc[7]*inv) << 16);
        }
        *(uint4*)(Agg + rl * 72 + q) = p;
    }
}

// ---------------- fused gather + GEMM1 + sigmoid -> t1 ---------------------
// 128 threads / 32-row tile, grid 3125.
__global__ __launch_bounds__(128) void aggemm1_k(
    const unsigned short* __restrict__ featbf, const int* __restrict__ off,
    const int* __restrict__ ssrc, const unsigned short* __restrict__ img,
    const float* __restrict__ bias, unsigned short* __restrict__ t1, int N)
{
    __shared__ alignas(16) unsigned short Agg[32 * 72];   // 4.6 KB

    const int tid = threadIdx.x;
    const int rowB = blockIdx.x * 32;
    const int w = tid >> 6, lane = tid & 63;
    const int m = lane & 15, quad = lane >> 4;
    const int row0 = rowB + w * 16;

    gather_tile_wave(featbf, off, ssrc, Agg, rowB, N, w, lane);

    const short8* Wf = (const short8*)(img + W1F_OFF);
    floatx4 acc[4];
    #pragma unroll
    for (int c = 0; c < 4; c++) acc[c] = (floatx4){0.f, 0.f, 0.f, 0.f};
    #pragma unroll
    for (int kk = 0; kk < 2; kk++) {
        short8 a = *(const short8*)(Agg + (w * 16 + m) * 72 + kk * 32 + quad * 8);
        #pragma unroll
        for (int c = 0; c < 4; c++) {
            short8 b = Wf[((c * 2 + kk) * 4 + quad) * 16 + m];
            acc[c] = __builtin_amdgcn_mfma_f32_16x16x32_bf16(a, b, acc[c], 0, 0, 0);
        }
    }
    bool dzr[4];
    int rows[4];
    #pragma unroll
    for (int r = 0; r < 4; r++) {
        rows[r] = row0 + quad * 4 + r;
        dzr[r] = (rows[r] < N) ? (off[rows[r] + 1] == off[rows[r]]) : false;
    }
    #pragma unroll
    for (int c = 0; c < 4; c++) {
        int col = c * 16 + m;
        float bv = bias[col];
        #pragma unroll
        for (int r = 0; r < 4; r++) {
            if (rows[r] < N) {
                float v = dzr[r] ? 0.5f : sigmoidf(acc[c][r] + bv);
                t1[(size_t)rows[r] * 64 + col] = f2bf(v);
            }
        }
    }
}

// ---------------- fused gather + triple-GEMM -> out ------------------------
// 128 threads / 32-row tile; LDS: T2[0,2304) | Agg/H3h[2304,4608) shorts.
// Every LDS row is touched only by its owning wave -> in-wave ordering
// (lgkmcnt) is sufficient, no __syncthreads anywhere.
__global__ __launch_bounds__(128) void aggep3_k(
    const unsigned short* __restrict__ t1, const int* __restrict__ off,
    const int* __restrict__ ssrc, const unsigned short* __restrict__ img,
    const float* __restrict__ b2, const float* __restrict__ b3,
    const float* __restrict__ b4, float* __restrict__ out, int N)
{
    __shared__ alignas(16) unsigned short SM[4608];   // 9.2 KB
    unsigned short* T2  = SM;            // 32 x 72
    unsigned short* Agg = SM + 2304;     // 32 x 72 (dead after phase 0)
    unsigned short* H3h = SM + 2304;     // 32 x 72 (aliases Agg)

    const int tid = threadIdx.x;
    const int rowB = blockIdx.x * 32;
    const int w = tid >> 6, lane = tid & 63;
    const int m = lane & 15, quad = lane >> 4;
    const int row0 = rowB + w * 16;

    gather_tile_wave(t1, off, ssrc, Agg, rowB, N, w, lane);

    // ---- phase 0: T2 = sigmoid(Agg @ W2 + b2) ----
    {
        const short8* Wf = (const short8*)(img + W2F_OFF);
        floatx4 acc[4];
        #pragma unroll
        for (int c = 0; c < 4; c++) acc[c] = (floatx4){0.f, 0.f, 0.f, 0.f};
        #pragma unroll
        for (int kk = 0; kk < 2; kk++) {
            short8 a = *(const short8*)(Agg + (w * 16 + m) * 72 + kk * 32 + quad * 8);
            #pragma unroll
            for (int c = 0; c < 4; c++) {
                short8 b = Wf[((c * 2 + kk) * 4 + quad) * 16 + m];
                acc[c] = __builtin_amdgcn_mfma_f32_16x16x32_bf16(a, b, acc[c], 0, 0, 0);
            }
        }
        bool dzr[4];
        #pragma unroll
        for (int r = 0; r < 4; r++) {
            int row = row0 + quad * 4 + r;
            dzr[r] = (row < N) ? (off[row + 1] == off[row]) : false;
        }
        #pragma unroll
        for (int c = 0; c < 4; c++) {
            int col = c * 16 + m;
            float bv = b2[col];
            #pragma unroll
            for (int r = 0; r < 4; r++) {
                int rl = w * 16 + quad * 4 + r;
                float v = dzr[r] ? 0.5f : sigmoidf(acc[c][r] + bv);
                T2[rl * 72 + col] = f2bf(v);
            }
        }
    }

    // ---- phases 1&2 split-K: per half, H3h = relu(T2@W3half+b3half),
    //      then acc2 += H3h @ W4[khalf] ----
    floatx4 acc2[3];
    #pragma unroll
    for (int c = 0; c < 3; c++) acc2[c] = (floatx4){0.f, 0.f, 0.f, 0.f};
    const short8* Wf3 = (const short8*)(img + W3F_OFF);
    const short8* Wf4 = (const short8*)(img + W4F_OFF);

    #pragma unroll
    for (int half = 0; half < 2; half++) {
        floatx4 acc[4];
        #pragma unroll
        for (int c = 0; c < 4; c++) acc[c] = (floatx4){0.f, 0.f, 0.f, 0.f};
        #pragma unroll
        for (int kk = 0; kk < 2; kk++) {
            short8 a = *(const short8*)(T2 + (w * 16 + m) * 72 + kk * 32 + quad * 8);
            #pragma unroll
            for (int c = 0; c < 4; c++) {
                short8 b = Wf3[(((half * 4 + c) * 2 + kk) * 4 + quad) * 16 + m];
                acc[c] = __builtin_amdgcn_mfma_f32_16x16x32_bf16(a, b, acc[c], 0, 0, 0);
            }
        }
        #pragma unroll
        for (int c = 0; c < 4; c++) {
            int col = c * 16 + m;
            float bv = b3[half * 64 + col];
            #pragma unroll
            for (int r = 0; r < 4; r++) {
                int rl = w * 16 + quad * 4 + r;
                H3h[rl * 72 + col] = f2bf(fmaxf(acc[c][r] + bv, 0.f));
            }
        }
        #pragma unroll
        for (int kk2 = 0; kk2 < 2; kk2++) {
            short8 a = *(const short8*)(H3h + (w * 16 + m) * 72 + kk2 * 32 + quad * 8);
            #pragma unroll
            for (int c = 0; c < 3; c++) {
                short8 b = Wf4[((c * 4 + half * 2 + kk2) * 4 + quad) * 16 + m];
                acc2[c] = __builtin_amdgcn_mfma_f32_16x16x32_bf16(a, b, acc2[c], 0, 0, 0);
            }
        }
    }

    // ---- store out = acc2 + b4 ----
    #pragma unroll
    for (int c = 0; c < 3; c++) {
        int col = c * 16 + m;
        if (col < 40) {
            float bv = b4[col];
            #pragma unroll
            for (int r = 0; r < 4; r++) {
                int row = row0 + quad * 4 + r;
                if (row < N) out[(size_t)row * 40 + col] = acc2[c][r] + bv;
            }
        }
    }
}

extern "C" void kernel_launch(void* const* d_in, const int* in_sizes, int n_in,
                              void* d_out, int out_size, void* d_ws, size_t ws_size,
                              hipStream_t stream)
{
    const float* feat = (const float*)d_in[0];
    const int*   eidx = (const int*)d_in[1];
    const float* W1 = (const float*)d_in[2];
    const float* b1 = (const float*)d_in[3];
    const float* W2 = (const float*)d_in[4];
    const float* b2 = (const float*)d_in[5];
    const float* W3 = (const float*)d_in[6];
    const float* b3 = (const float*)d_in[7];
    const float* W4 = (const float*)d_in[8];
    const float* b4 = (const float*)d_in[9];

    const int N = in_sizes[0] / 64;
    const int E = in_sizes[1] / 2;
    const int* src = eidx;
    const int* dst = eidx + E;

    const int NBUCK = (N + CNODES - 1) / CNODES;   // 196

    unsigned short* featbf = (unsigned short*)d_ws;            // N*64 bf16
    unsigned short* t1     = featbf + (size_t)N * 64;          // N*64 bf16
    unsigned short* img    = t1     + (size_t)N * 64;          // WIMG_TOT
    int*   off   = (int*)(img + WIMG_TOT);                     // N+1
    int*   ccur  = off + (N + 1);                              // NBUCK
    int*   ssrc  = ccur + NBUCK;                               // E
    int*   arena = ssrc + E;                                   // NBUCK*CAP
    float* out   = (float*)d_out;

    hipMemsetAsync(ccur, 0, (size_t)NBUCK * sizeof(int), stream);

    const int gP  = (E + EPB - 1) / EPB;
    const int g32 = (N + 31) / 32;
    const int n8  = N * 64 / 8;
    const int gPC = (n8 + WIMG_TOT + PTHR - 1) / PTHR;

    // CSR partition + prep (merged, 512thr), then per-bucket counting sort
    part_prep_k<<<gP + gPC, dim3(PTHR), 0, stream>>>(src, dst, ccur, arena, E,
                                                     NBUCK, gP, feat, featbf,
                                                     W1, W2, W3, W4, img, n8);
    csr_fine<<<NBUCK, dim3(1024), 0, stream>>>(arena, ccur, off, ssrc, N, E, NBUCK);

    // t1 = sigmoid(mean(featbf[src]) @ W1 + b1)   [fused, 0 barriers]
    aggemm1_k<<<g32, dim3(128), 0, stream>>>(featbf, off, ssrc, img, b1, t1, N);
    // out = relu(sigmoid(mean(t1[src])@W2+b2)@W3+b3)@W4 + b4  [fused, 0 barriers]
    aggep3_k<<<g32, dim3(128), 0, stream>>>(t1, off, ssrc, img, b2, b3, b4, out, N);
}

// Round 6
// 220.357 us; speedup vs baseline: 1.0240x; 1.0240x over previous
//
#include <hip/hip_runtime.h>

// HGCN on MI355X. logmap0(expmap0(v)) == v here, so the model reduces to:
//   t1 = sigmoid(segmean(feat@W1+b1)); t2 = sigmoid(segmean(t1@W2+b2))
//   out = relu(t2@W3+b3)@W4 + b4     (segmean commutes with the linear map;
//   deg-0 nodes: segmean = 0 -> value 0.5 exactly, handled via dz check)
// R1-R13: see session journal (atomic wall -> CSR; coarse buckets; bf16
//   gather rows; frag-packed weight image; wave-local zero-barrier MLP).
// R14: baseline re-anchor, 229.4us. Gathers latency-bound (occ ~30%).
// R15: FAILED (1356us). LDS float atomicAdd = CAS loop, not ds_add_f32.
// R16: FAILED (240us). Fine buckets -> write-amp; sort once, not per-layer.
// R17: WIN (219us). csr_fine@1024thr; gathers 128thr/32-row; aggep3 59->48.
// R18: NET LOSS (225.6). part_prep@512+shuffle scan WON ~13us (kept);
//   16-deep single-chain gather LOST: VGPR 60->68 only => regalloc capped
//   in-flight at ~8; deg<16 rows (47%) fell to 4-deep tail. Lesson: depth
//   must come from INDEPENDENT chains, not a longer single chain.
// R19: 1-wave/64-thr blocks (16 rows, grid 6250, zero barriers, ~2x resident
//   waves) + DUAL-ROW gather: each 8-lane group runs rows (g,g+8) as two
//   concurrent 8-deep chains -> 16 loads in flight for deg>=8 (99%) rows.
//   __launch_bounds__(64,4) caps VGPR 128 (16 waves/CU). Predicted 190-200us;
//   if gather unchanged -> L2-miss-rate wall, pivot to traffic reduction.

constexpr int CSHIFT = 9;               // 512 nodes per coarse bucket
constexpr int CNODES = 1 << CSHIFT;
constexpr int EPB    = 4096;            // edges per partition block
constexpr int PTHR   = 512;             // partition block threads (R18)
constexpr int EPT    = EPB / PTHR;      // 8 edges/thread
constexpr int CAP    = 16384;           // arena capacity per bucket (mean 8163)

// frag-packed bf16 weight image (shorts). Fragment = 16 lanes x 8 shorts =
// 128 shorts; flat idx = (((c*KK + kk)*4 + quad)*16 + m)*8 + j.
constexpr int W1F_OFF = 0;              // 4x2x4 frags  = 4096 shorts
constexpr int W2F_OFF = 4096;           // 4096
constexpr int W3F_OFF = 8192;           // 8x2x4 frags  = 8192
constexpr int W4F_OFF = 16384;          // 3x4x4 frags  = 6144 (cols padded 48)
constexpr int WIMG_TOT = 22528;

typedef __attribute__((ext_vector_type(8))) short short8;   // 8 bf16
typedef __attribute__((ext_vector_type(4))) float floatx4;  // MFMA acc

__device__ __forceinline__ float sigmoidf(float x) {
    return 1.0f / (1.0f + __expf(-x));
}
__device__ __forceinline__ unsigned short f2bf(float f) {   // RNE f32->bf16
    unsigned int u = __float_as_uint(f);
    u = (u + 0x7FFFu + ((u >> 16) & 1u)) >> 16;
    return (unsigned short)u;
}

// ---------------- CSR partition + one-time prep (merged launch) ------------
__global__ __launch_bounds__(512) void part_prep_k(
    const int* __restrict__ src, const int* __restrict__ dst,
    int* __restrict__ ccur, int* __restrict__ arena, int E, int NBUCK, int gP,
    const float* __restrict__ feat, unsigned short* __restrict__ featbf,
    const float* __restrict__ W1, const float* __restrict__ W2,
    const float* __restrict__ W3, const float* __restrict__ W4,
    unsigned short* __restrict__ img, int n8)
{
    __shared__ int  hist[256];
    __shared__ int  exoff[256];
    __shared__ int  lcur[256];
    __shared__ int  gbase[256];
    __shared__ int  wsum[4];
    __shared__ int  stage[EPB];
    __shared__ unsigned char stageB[EPB];

    const int tid = threadIdx.x;

    if ((int)blockIdx.x >= gP) {
        // ---- prep path ----
        int i = ((int)blockIdx.x - gP) * PTHR + tid;
        if (i < n8) {
            const float4* p = (const float4*)feat + (size_t)i * 2;
            float4 a = p[0], b = p[1];
            uint4 o;
            o.x = (unsigned)f2bf(a.x) | ((unsigned)f2bf(a.y) << 16);
            o.y = (unsigned)f2bf(a.z) | ((unsigned)f2bf(a.w) << 16);
            o.z = (unsigned)f2bf(b.x) | ((unsigned)f2bf(b.y) << 16);
            o.w = (unsigned)f2bf(b.z) | ((unsigned)f2bf(b.w) << 16);
            ((uint4*)featbf)[i] = o;
            return;
        }
        int t = i - n8;
        if (t >= WIMG_TOT) return;
        float v = 0.f;
        int s = t;
        if (s < W2F_OFF) {                       // W1 [64x64]
            int j = s & 7, m = (s >> 3) & 15, q = (s >> 7) & 3, kk = (s >> 9) & 1, c = s >> 10;
            v = W1[(kk * 32 + q * 8 + j) * 64 + c * 16 + m];
        } else if (s < W3F_OFF) {                // W2 [64x64]
            s -= W2F_OFF;
            int j = s & 7, m = (s >> 3) & 15, q = (s >> 7) & 3, kk = (s >> 9) & 1, c = s >> 10;
            v = W2[(kk * 32 + q * 8 + j) * 64 + c * 16 + m];
        } else if (s < W4F_OFF) {                // W3 [64x128]
            s -= W3F_OFF;
            int j = s & 7, m = (s >> 3) & 15, q = (s >> 7) & 3, kk = (s >> 9) & 1, c = s >> 10;
            v = W3[(kk * 32 + q * 8 + j) * 128 + c * 16 + m];
        } else {                                 // W4 [128x40], cols padded 48
            s -= W4F_OFF;
            int j = s & 7, m = (s >> 3) & 15, q = (s >> 7) & 3, kk = (s >> 9) & 3, c = s >> 11;
            int n = c * 16 + m;
            if (n < 40) v = W4[(kk * 32 + q * 8 + j) * 40 + n];
        }
        img[t] = f2bf(v);
        return;
    }

    // ---- partition path (512 threads) ----
    const int e0  = blockIdx.x * EPB;
    const int ec  = min(EPB, E - e0);
    const int lane = tid & 63, wid = tid >> 6;

    int pk[EPT], bk[EPT];
    if (tid < 256) hist[tid] = 0;
    __syncthreads();
    #pragma unroll
    for (int j = 0; j < EPT; j++) {
        int idx = tid + j * PTHR;
        if (idx < ec) {
            int s = src[e0 + idx];
            int d = dst[e0 + idx];
            bk[j] = d >> CSHIFT;
            pk[j] = s | ((d & (CNODES - 1)) << 17);
            atomicAdd(&hist[bk[j]], 1);
        } else bk[j] = -1;
    }
    __syncthreads();
    // shuffle scan of hist[256] on waves 0-3 (wave-uniform branch)
    int h = 0, v = 0;
    if (tid < 256) {
        h = hist[tid];
        v = h;
        #pragma unroll
        for (int d = 1; d < 64; d <<= 1) {
            int t = __shfl_up(v, d);
            if (lane >= d) v += t;
        }
        if (lane == 63) wsum[wid] = v;
    }
    __syncthreads();
    if (tid == 0) {
        int s = 0;
        #pragma unroll
        for (int k = 0; k < 4; k++) { int t = wsum[k]; wsum[k] = s; s += t; }
    }
    __syncthreads();
    if (tid < 256) {
        int ex = wsum[wid] + v - h;
        int gb = 0;
        if (tid < NBUCK && h > 0) gb = atomicAdd(ccur + tid, h);
        exoff[tid] = ex;
        lcur[tid]  = ex;
        gbase[tid] = gb;
    }
    __syncthreads();
    #pragma unroll
    for (int j = 0; j < EPT; j++) {
        if (bk[j] >= 0) {
            int l = atomicAdd(&lcur[bk[j]], 1);
            stage[l]  = pk[j];
            stageB[l] = (unsigned char)bk[j];
        }
    }
    __syncthreads();
    for (int i = tid; i < ec; i += PTHR) {
        int b = stageB[i];
        arena[(size_t)b * CAP + gbase[b] + (i - exoff[b])] = stage[i];
    }
}

// One 1024-thread block per coarse bucket: 16 waves hide the arena read +
// LDS-atomic latency; inline scan of bucket counts -> cbeg; LDS counting
// sort over 512 nodes -> off/ssrc.
__global__ __launch_bounds__(1024) void csr_fine(const int* __restrict__ arena,
                                                 const int* __restrict__ ccur,
                                                 int* __restrict__ off,
                                                 int* __restrict__ ssrc,
                                                 int N, int E, int NBUCK) {
    __shared__ int part[256];
    __shared__ int cnt[CNODES];
    __shared__ int cur[CNODES];
    __shared__ int wpre[8];
    const int b = blockIdx.x;
    const int node0 = b << CSHIFT;
    const int tid = threadIdx.x;
    const int lane = tid & 63, wid = tid >> 6;

    if (tid < 256) part[tid] = (tid < NBUCK) ? ccur[tid] : 0;
    __syncthreads();
    for (int d = 1; d < 256; d <<= 1) {
        int v = 0;
        if (tid < 256 && tid >= d) v = part[tid - d];
        __syncthreads();
        if (tid < 256 && tid >= d) part[tid] += v;
        __syncthreads();
    }
    const int cbeg = (b > 0) ? part[b - 1] : 0;
    const int ec   = min(ccur[b], CAP);
    if (b == 0 && tid == 0) off[N] = E;

    if (tid < CNODES) cnt[tid] = 0;
    __syncthreads();
    const int* pe = arena + (size_t)b * CAP;
    for (int i = tid; i < ec; i += 1024)
        atomicAdd(&cnt[(pe[i] >> 17) & (CNODES - 1)], 1);
    __syncthreads();

    int c = (tid < CNODES) ? cnt[tid] : 0;
    int v = c;
    #pragma unroll
    for (int d = 1; d < 64; d <<= 1) {
        int t = __shfl_up(v, d);
        if (lane >= d) v += t;
    }
    if (tid < CNODES && lane == 63) wpre[wid] = v;
    __syncthreads();
    if (tid == 0) {
        int s = 0;
        #pragma unroll
        for (int k = 0; k < CNODES / 64; k++) { int t = wpre[k]; wpre[k] = s; s += t; }
    }
    __syncthreads();
    if (tid < CNODES) {
        int ex = wpre[wid] + v - c;
        cur[tid] = ex;
        int node = node0 + tid;
        if (node < N) off[node] = cbeg + ex;
    }
    __syncthreads();
    for (int i = tid; i < ec; i += 1024) {
        int p = pe[i];
        int pos = cbeg + atomicAdd(&cur[(p >> 17) & (CNODES - 1)], 1);
        ssrc[pos] = p & 0x1FFFF;
    }
}

// ---------------- dual-row wave gather: 16 rows/wave, 2 chains/lane --------
// 8-lane group g owns rows (g, g+8): two INDEPENDENT 8-deep load chains run
// concurrently in the joint loop -> ~16 loads in flight for deg>=8 rows.
#define ACC8T(A, v)                                 \
    A[0] += __uint_as_float((v).x << 16);           \
    A[1] += __uint_as_float((v).x & 0xFFFF0000u);   \
    A[2] += __uint_as_float((v).y << 16);           \
    A[3] += __uint_as_float((v).y & 0xFFFF0000u);   \
    A[4] += __uint_as_float((v).z << 16);           \
    A[5] += __uint_as_float((v).z & 0xFFFF0000u);   \
    A[6] += __uint_as_float((v).w << 16);           \
    A[7] += __uint_as_float((v).w & 0xFFFF0000u);

#define LD8(P, base, i)                                             \
    {                                                               \
        int s0 = ssrc[i],     s1 = ssrc[(i)+1];                     \
        int s2 = ssrc[(i)+2], s3 = ssrc[(i)+3];                     \
        int s4 = ssrc[(i)+4], s5 = ssrc[(i)+5];                     \
        int s6 = ssrc[(i)+6], s7 = ssrc[(i)+7];                     \
        uint4 v0 = *(const uint4*)(h + (size_t)s0 * 64 + q);        \
        uint4 v1 = *(const uint4*)(h + (size_t)s1 * 64 + q);        \
        uint4 v2 = *(const uint4*)(h + (size_t)s2 * 64 + q);        \
        uint4 v3 = *(const uint4*)(h + (size_t)s3 * 64 + q);        \
        uint4 v4 = *(const uint4*)(h + (size_t)s4 * 64 + q);        \
        uint4 v5 = *(const uint4*)(h + (size_t)s5 * 64 + q);        \
        uint4 v6 = *(const uint4*)(h + (size_t)s6 * 64 + q);        \
        uint4 v7 = *(const uint4*)(h + (size_t)s7 * 64 + q);        \
        ACC8T(P, v0); ACC8T(P, v1); ACC8T(P, v2); ACC8T(P, v3);     \
        ACC8T(P, v4); ACC8T(P, v5); ACC8T(P, v6); ACC8T(P, v7);     \
    }

__device__ __forceinline__ void gather_rows16(
    const unsigned short* __restrict__ h, const int* __restrict__ off,
    const int* __restrict__ ssrc, unsigned short* Agg, int rowB, int N,
    int lane)
{
    const int grp = lane >> 3;
    const int q   = (lane & 7) * 8;
    const int rl0 = grp, rl1 = grp + 8;
    const int g0 = rowB + rl0, g1 = rowB + rl1;

    float acc0[8] = {0.f, 0.f, 0.f, 0.f, 0.f, 0.f, 0.f, 0.f};
    float acc1[8] = {0.f, 0.f, 0.f, 0.f, 0.f, 0.f, 0.f, 0.f};
    int i0 = 0, e0 = 0, i1 = 0, e1 = 0;
    if (g0 < N) { i0 = off[g0]; e0 = off[g0 + 1]; }
    if (g1 < N) { i1 = off[g1]; e1 = off[g1 + 1]; }
    const int d0 = e0 - i0, d1 = e1 - i1;

    // joint loop: two independent 8-deep chains (16 loads in flight)
    while (i0 + 8 <= e0 && i1 + 8 <= e1) {
        LD8(acc0, h, i0);
        LD8(acc1, h, i1);
        i0 += 8; i1 += 8;
    }
    // drain row0
    for (; i0 + 8 <= e0; i0 += 8) LD8(acc0, h, i0);
    for (; i0 + 2 <= e0; i0 += 2) {
        int s0 = ssrc[i0], s1 = ssrc[i0 + 1];
        uint4 v0 = *(const uint4*)(h + (size_t)s0 * 64 + q);
        uint4 v1 = *(const uint4*)(h + (size_t)s1 * 64 + q);
        ACC8T(acc0, v0); ACC8T(acc0, v1);
    }
    for (; i0 < e0; i0++) {
        uint4 v = *(const uint4*)(h + (size_t)ssrc[i0] * 64 + q);
        ACC8T(acc0, v);
    }
    // drain row1
    for (; i1 + 8 <= e1; i1 += 8) LD8(acc1, h, i1);
    for (; i1 + 2 <= e1; i1 += 2) {
        int s0 = ssrc[i1], s1 = ssrc[i1 + 1];
        uint4 v0 = *(const uint4*)(h + (size_t)s0 * 64 + q);
        uint4 v1 = *(const uint4*)(h + (size_t)s1 * 64 + q);
        ACC8T(acc1, v0); ACC8T(acc1, v1);
    }
    for (; i1 < e1; i1++) {
        uint4 v = *(const uint4*)(h + (size_t)ssrc[i1] * 64 + q);
        ACC8T(acc1, v);
    }

    // pack both rows (v_rcp: 2^-22 rel err, absorbed by bf16 round)
    float inv0 = __builtin_amdgcn_rcpf((float)max(d0, 1));
    float inv1 = __builtin_amdgcn_rcpf((float)max(d1, 1));
    uint4 p0, p1;
    p0.x = (unsigned)f2bf(acc0[0]*inv0) | ((unsigned)f2bf(acc0[1]*inv0) << 16);
    p0.y = (unsigned)f2bf(acc0[2]*inv0) | ((unsigned)f2bf(acc0[3]*inv0) << 16);
    p0.z = (unsigned)f2bf(acc0[4]*inv0) | ((unsigned)f2bf(acc0[5]*inv0) << 16);
    p0.w = (unsigned)f2bf(acc0[6]*inv0) | ((unsigned)f2bf(acc0[7]*inv0) << 16);
    p1.x = (unsigned)f2bf(acc1[0]*inv1) | ((unsigned)f2bf(acc1[1]*inv1) << 16);
    p1.y = (unsigned)f2bf(acc1[2]*inv1) | ((unsigned)f2bf(acc1[3]*inv1) << 16);
    p1.z = (unsigned)f2bf(acc1[4]*inv1) | ((unsigned)f2bf(acc1[5]*inv1) << 16);
    p1.w = (unsigned)f2bf(acc1[6]*inv1) | ((unsigned)f2bf(acc1[7]*inv1) << 16);
    *(uint4*)(Agg + rl0 * 72 + q) = p0;
    *(uint4*)(Agg + rl1 * 72 + q) = p1;
}

// ---------------- fused gather + GEMM1 + sigmoid -> t1 ---------------------
// 1 wave / 16-row tile, grid 6250, zero barriers.
__global__ __launch_bounds__(64, 4) void aggemm1_k(
    const unsigned short* __restrict__ featbf, const int* __restrict__ off,
    const int* __restrict__ ssrc, const unsigned short* __restrict__ img,
    const float* __restrict__ bias, unsigned short* __restrict__ t1, int N)
{
    __shared__ alignas(16) unsigned short Agg[16 * 72];   // 2.3 KB

    const int lane = threadIdx.x;
    const int rowB = blockIdx.x * 16;
    const int m = lane & 15, quad = lane >> 4;

    gather_rows16(featbf, off, ssrc, Agg, rowB, N, lane);

    const short8* Wf = (const short8*)(img + W1F_OFF);
    floatx4 acc[4];
    #pragma unroll
    for (int c = 0; c < 4; c++) acc[c] = (floatx4){0.f, 0.f, 0.f, 0.f};
    #pragma unroll
    for (int kk = 0; kk < 2; kk++) {
        short8 a = *(const short8*)(Agg + m * 72 + kk * 32 + quad * 8);
        #pragma unroll
        for (int c = 0; c < 4; c++) {
            short8 b = Wf[((c * 2 + kk) * 4 + quad) * 16 + m];
            acc[c] = __builtin_amdgcn_mfma_f32_16x16x32_bf16(a, b, acc[c], 0, 0, 0);
        }
    }
    bool dzr[4];
    int rows[4];
    #pragma unroll
    for (int r = 0; r < 4; r++) {
        rows[r] = rowB + quad * 4 + r;
        dzr[r] = (rows[r] < N) ? (off[rows[r] + 1] == off[rows[r]]) : false;
    }
    #pragma unroll
    for (int c = 0; c < 4; c++) {
        int col = c * 16 + m;
        float bv = bias[col];
        #pragma unroll
        for (int r = 0; r < 4; r++) {
            if (rows[r] < N) {
                float v = dzr[r] ? 0.5f : sigmoidf(acc[c][r] + bv);
                t1[(size_t)rows[r] * 64 + col] = f2bf(v);
            }
        }
    }
}

// ---------------- fused gather + triple-GEMM -> out ------------------------
// 1 wave / 16-row tile; LDS: T2[0,1152) | Agg/H3h[1152,2304) shorts.
// Single wave -> in-wave ordering (lgkmcnt) suffices, no barriers.
__global__ __launch_bounds__(64, 4) void aggep3_k(
    const unsigned short* __restrict__ t1, const int* __restrict__ off,
    const int* __restrict__ ssrc, const unsigned short* __restrict__ img,
    const float* __restrict__ b2, const float* __restrict__ b3,
    const float* __restrict__ b4, float* __restrict__ out, int N)
{
    __shared__ alignas(16) unsigned short SM[2304];   // 4.6 KB
    unsigned short* T2  = SM;            // 16 x 72
    unsigned short* Agg = SM + 1152;     // 16 x 72 (dead after phase 0)
    unsigned short* H3h = SM + 1152;     // aliases Agg

    const int lane = threadIdx.x;
    const int rowB = blockIdx.x * 16;
    const int m = lane & 15, quad = lane >> 4;

    gather_rows16(t1, off, ssrc, Agg, rowB, N, lane);

    // ---- phase 0: T2 = sigmoid(Agg @ W2 + b2) ----
    {
        const short8* Wf = (const short8*)(img + W2F_OFF);
        floatx4 acc[4];
        #pragma unroll
        for (int c = 0; c < 4; c++) acc[c] = (floatx4){0.f, 0.f, 0.f, 0.f};
        #pragma unroll
        for (int kk = 0; kk < 2; kk++) {
            short8 a = *(const short8*)(Agg + m * 72 + kk * 32 + quad * 8);
            #pragma unroll
            for (int c = 0; c < 4; c++) {
                short8 b = Wf[((c * 2 + kk) * 4 + quad) * 16 + m];
                acc[c] = __builtin_amdgcn_mfma_f32_16x16x32_bf16(a, b, acc[c], 0, 0, 0);
            }
        }
        bool dzr[4];
        #pragma unroll
        for (int r = 0; r < 4; r++) {
            int row = rowB + quad * 4 + r;
            dzr[r] = (row < N) ? (off[row + 1] == off[row]) : false;
        }
        #pragma unroll
        for (int c = 0; c < 4; c++) {
            int col = c * 16 + m;
            float bv = b2[col];
            #pragma unroll
            for (int r = 0; r < 4; r++) {
                int rl = quad * 4 + r;
                float v = dzr[r] ? 0.5f : sigmoidf(acc[c][r] + bv);
                T2[rl * 72 + col] = f2bf(v);
            }
        }
    }

    // ---- phases 1&2 split-K: per half, H3h = relu(T2@W3half+b3half),
    //      then acc2 += H3h @ W4[khalf] ----
    floatx4 acc2[3];
    #pragma unroll
    for (int c = 0; c < 3; c++) acc2[c] = (floatx4){0.f, 0.f, 0.f, 0.f};
    const short8* Wf3 = (const short8*)(img + W3F_OFF);
    const short8* Wf4 = (const short8*)(img + W4F_OFF);

    #pragma unroll
    for (int half = 0; half < 2; half++) {
        floatx4 acc[4];
        #pragma unroll
        for (int c = 0; c < 4; c++) acc[c] = (floatx4){0.f, 0.f, 0.f, 0.f};
        #pragma unroll
        for (int kk = 0; kk < 2; kk++) {
            short8 a = *(const short8*)(T2 + m * 72 + kk * 32 + quad * 8);
            #pragma unroll
            for (int c = 0; c < 4; c++) {
                short8 b = Wf3[(((half * 4 + c) * 2 + kk) * 4 + quad) * 16 + m];
                acc[c] = __builtin_amdgcn_mfma_f32_16x16x32_bf16(a, b, acc[c], 0, 0, 0);
            }
        }
        #pragma unroll
        for (int c = 0; c < 4; c++) {
            int col = c * 16 + m;
            float bv = b3[half * 64 + col];
            #pragma unroll
            for (int r = 0; r < 4; r++) {
                int rl = quad * 4 + r;
                H3h[rl * 72 + col] = f2bf(fmaxf(acc[c][r] + bv, 0.f));
            }
        }
        #pragma unroll
        for (int kk2 = 0; kk2 < 2; kk2++) {
            short8 a = *(const short8*)(H3h + m * 72 + kk2 * 32 + quad * 8);
            #pragma unroll
            for (int c = 0; c < 3; c++) {
                short8 b = Wf4[((c * 4 + half * 2 + kk2) * 4 + quad) * 16 + m];
                acc2[c] = __builtin_amdgcn_mfma_f32_16x16x32_bf16(a, b, acc2[c], 0, 0, 0);
            }
        }
    }

    // ---- store out = acc2 + b4 ----
    #pragma unroll
    for (int c = 0; c < 3; c++) {
        int col = c * 16 + m;
        if (col < 40) {
            float bv = b4[col];
            #pragma unroll
            for (int r = 0; r < 4; r++) {
                int row = rowB + quad * 4 + r;
                if (row < N) out[(size_t)row * 40 + col] = acc2[c][r] + bv;
            }
        }
    }
}

extern "C" void kernel_launch(void* const* d_in, const int* in_sizes, int n_in,
                              void* d_out, int out_size, void* d_ws, size_t ws_size,
                              hipStream_t stream)
{
    const float* feat = (const float*)d_in[0];
    const int*   eidx = (const int*)d_in[1];
    const float* W1 = (const float*)d_in[2];
    const float* b1 = (const float*)d_in[3];
    const float* W2 = (const float*)d_in[4];
    const float* b2 = (const float*)d_in[5];
    const float* W3 = (const float*)d_in[6];
    const float* b3 = (const float*)d_in[7];
    const float* W4 = (const float*)d_in[8];
    const float* b4 = (const float*)d_in[9];

    const int N = in_sizes[0] / 64;
    const int E = in_sizes[1] / 2;
    const int* src = eidx;
    const int* dst = eidx + E;

    const int NBUCK = (N + CNODES - 1) / CNODES;   // 196

    unsigned short* featbf = (unsigned short*)d_ws;            // N*64 bf16
    unsigned short* t1     = featbf + (size_t)N * 64;          // N*64 bf16
    unsigned short* img    = t1     + (size_t)N * 64;          // WIMG_TOT
    int*   off   = (int*)(img + WIMG_TOT);                     // N+1
    int*   ccur  = off + (N + 1);                              // NBUCK
    int*   ssrc  = ccur + NBUCK;                               // E
    int*   arena = ssrc + E;                                   // NBUCK*CAP
    float* out   = (float*)d_out;

    hipMemsetAsync(ccur, 0, (size_t)NBUCK * sizeof(int), stream);

    const int gP  = (E + EPB - 1) / EPB;
    const int g16 = (N + 15) / 16;
    const int n8  = N * 64 / 8;
    const int gPC = (n8 + WIMG_TOT + PTHR - 1) / PTHR;

    // CSR partition + prep (merged, 512thr), then per-bucket counting sort
    part_prep_k<<<gP + gPC, dim3(PTHR), 0, stream>>>(src, dst, ccur, arena, E,
                                                     NBUCK, gP, feat, featbf,
                                                     W1, W2, W3, W4, img, n8);
    csr_fine<<<NBUCK, dim3(1024), 0, stream>>>(arena, ccur, off, ssrc, N, E, NBUCK);

    // t1 = sigmoid(mean(featbf[src]) @ W1 + b1)   [1 wave/block, 0 barriers]
    aggemm1_k<<<g16, dim3(64), 0, stream>>>(featbf, off, ssrc, img, b1, t1, N);
    // out = relu(sigmoid(mean(t1[src])@W2+b2)@W3+b3)@W4 + b4
    aggep3_k<<<g16, dim3(64), 0, stream>>>(t1, off, ssrc, img, b2, b3, b4, out, N);
}

// Round 7
// 214.457 us; speedup vs baseline: 1.0522x; 1.0275x over previous
//
#include <hip/hip_runtime.h>

// HGCN on MI355X. logmap0(expmap0(v)) == v here, so the model reduces to:
//   t1 = sigmoid(segmean(feat@W1+b1)); t2 = sigmoid(segmean(t1@W2+b2))
//   out = relu(t2@W3+b3)@W4 + b4     (segmean commutes with the linear map;
//   deg-0 nodes: segmean = 0 -> value 0.5 exactly, handled via dz check)
// R1-R13: see session journal (atomic wall -> CSR; coarse buckets; bf16
//   gather rows; frag-packed weight image; wave-local zero-barrier MLP).
// R14: baseline re-anchor, 229.4us. Gathers latency-bound (occ ~30%).
// R15: FAILED (1356us). LDS float atomicAdd = CAS loop, not ds_add_f32.
// R16: FAILED (240us). Fine buckets -> write-amp; sort once, not per-layer.
// R17: WIN (219us). csr_fine@1024thr; gathers 128thr/32-row; aggep3 59->48.
// R18: NET LOSS (225.6). part_prep@512 won ~13us (kept); 16-deep single
//   chain lost (regalloc caps in-flight ~8).
// R19: NULL (220.4). occ 22->34.5% but dur 48->51: gathers are NOT
//   concurrency-bound. Invariant ~2.0TB/s effective, FETCH 83MB vs 12.8MB
//   table => L2 thrash over random sources; 16x source reuse uncaptured.
// R20: SOURCE-CHUNK ORDERING. csr_fine sorts each row's edges by src>>14
//   (2MB chunks, 8 max): key = fine<<3|chunk, 4096 bins, 33KB LDS. All
//   blocks walk chunks in the same order -> concurrent source window
//   ~2-4MB = one XCD L2. Gathers unchanged (revert to best R17 config).
//   Predicted: gather FETCH 83->25-45MB, dur 48->30-38, total ~185us.
//   Null (FETCH unchanged) => request-rate wall, roofline next.

constexpr int CSHIFT = 9;               // 512 nodes per coarse bucket
constexpr int CNODES = 1 << CSHIFT;
constexpr int EPB    = 4096;            // edges per partition block
constexpr int PTHR   = 512;             // partition block threads (R18)
constexpr int EPT    = EPB / PTHR;      // 8 edges/thread
constexpr int CAP    = 16384;           // arena capacity per bucket (mean 8163)
constexpr int SSH    = 14;              // src chunk shift: 16K rows = 2MB bf16
constexpr int NCH    = 8;               // chunks (100K>>14 = 6.1 -> 7, pad 8)
constexpr int NBIN   = CNODES * NCH;    // 4096 sort bins per bucket

// frag-packed bf16 weight image (shorts). Fragment = 16 lanes x 8 shorts =
// 128 shorts; flat idx = (((c*KK + kk)*4 + quad)*16 + m)*8 + j.
constexpr int W1F_OFF = 0;              // 4x2x4 frags  = 4096 shorts
constexpr int W2F_OFF = 4096;           // 4096
constexpr int W3F_OFF = 8192;           // 8x2x4 frags  = 8192
constexpr int W4F_OFF = 16384;          // 3x4x4 frags  = 6144 (cols padded 48)
constexpr int WIMG_TOT = 22528;

typedef __attribute__((ext_vector_type(8))) short short8;   // 8 bf16
typedef __attribute__((ext_vector_type(4))) float floatx4;  // MFMA acc

__device__ __forceinline__ float sigmoidf(float x) {
    return 1.0f / (1.0f + __expf(-x));
}
__device__ __forceinline__ unsigned short f2bf(float f) {   // RNE f32->bf16
    unsigned int u = __float_as_uint(f);
    u = (u + 0x7FFFu + ((u >> 16) & 1u)) >> 16;
    return (unsigned short)u;
}

// ---------------- CSR partition + one-time prep (merged launch) ------------
__global__ __launch_bounds__(512) void part_prep_k(
    const int* __restrict__ src, const int* __restrict__ dst,
    int* __restrict__ ccur, int* __restrict__ arena, int E, int NBUCK, int gP,
    const float* __restrict__ feat, unsigned short* __restrict__ featbf,
    const float* __restrict__ W1, const float* __restrict__ W2,
    const float* __restrict__ W3, const float* __restrict__ W4,
    unsigned short* __restrict__ img, int n8)
{
    __shared__ int  hist[256];
    __shared__ int  exoff[256];
    __shared__ int  lcur[256];
    __shared__ int  gbase[256];
    __shared__ int  wsum[4];
    __shared__ int  stage[EPB];
    __shared__ unsigned char stageB[EPB];

    const int tid = threadIdx.x;

    if ((int)blockIdx.x >= gP) {
        // ---- prep path ----
        int i = ((int)blockIdx.x - gP) * PTHR + tid;
        if (i < n8) {
            const float4* p = (const float4*)feat + (size_t)i * 2;
            float4 a = p[0], b = p[1];
            uint4 o;
            o.x = (unsigned)f2bf(a.x) | ((unsigned)f2bf(a.y) << 16);
            o.y = (unsigned)f2bf(a.z) | ((unsigned)f2bf(a.w) << 16);
            o.z = (unsigned)f2bf(b.x) | ((unsigned)f2bf(b.y) << 16);
            o.w = (unsigned)f2bf(b.z) | ((unsigned)f2bf(b.w) << 16);
            ((uint4*)featbf)[i] = o;
            return;
        }
        int t = i - n8;
        if (t >= WIMG_TOT) return;
        float v = 0.f;
        int s = t;
        if (s < W2F_OFF) {                       // W1 [64x64]
            int j = s & 7, m = (s >> 3) & 15, q = (s >> 7) & 3, kk = (s >> 9) & 1, c = s >> 10;
            v = W1[(kk * 32 + q * 8 + j) * 64 + c * 16 + m];
        } else if (s < W3F_OFF) {                // W2 [64x64]
            s -= W2F_OFF;
            int j = s & 7, m = (s >> 3) & 15, q = (s >> 7) & 3, kk = (s >> 9) & 1, c = s >> 10;
            v = W2[(kk * 32 + q * 8 + j) * 64 + c * 16 + m];
        } else if (s < W4F_OFF) {                // W3 [64x128]
            s -= W3F_OFF;
            int j = s & 7, m = (s >> 3) & 15, q = (s >> 7) & 3, kk = (s >> 9) & 1, c = s >> 10;
            v = W3[(kk * 32 + q * 8 + j) * 128 + c * 16 + m];
        } else {                                 // W4 [128x40], cols padded 48
            s -= W4F_OFF;
            int j = s & 7, m = (s >> 3) & 15, q = (s >> 7) & 3, kk = (s >> 9) & 3, c = s >> 11;
            int n = c * 16 + m;
            if (n < 40) v = W4[(kk * 32 + q * 8 + j) * 40 + n];
        }
        img[t] = f2bf(v);
        return;
    }

    // ---- partition path (512 threads) ----
    const int e0  = blockIdx.x * EPB;
    const int ec  = min(EPB, E - e0);
    const int lane = tid & 63, wid = tid >> 6;

    int pk[EPT], bk[EPT];
    if (tid < 256) hist[tid] = 0;
    __syncthreads();
    #pragma unroll
    for (int j = 0; j < EPT; j++) {
        int idx = tid + j * PTHR;
        if (idx < ec) {
            int s = src[e0 + idx];
            int d = dst[e0 + idx];
            bk[j] = d >> CSHIFT;
            pk[j] = s | ((d & (CNODES - 1)) << 17);
            atomicAdd(&hist[bk[j]], 1);
        } else bk[j] = -1;
    }
    __syncthreads();
    // shuffle scan of hist[256] on waves 0-3 (wave-uniform branch)
    int h = 0, v = 0;
    if (tid < 256) {
        h = hist[tid];
        v = h;
        #pragma unroll
        for (int d = 1; d < 64; d <<= 1) {
            int t = __shfl_up(v, d);
            if (lane >= d) v += t;
        }
        if (lane == 63) wsum[wid] = v;
    }
    __syncthreads();
    if (tid == 0) {
        int s = 0;
        #pragma unroll
        for (int k = 0; k < 4; k++) { int t = wsum[k]; wsum[k] = s; s += t; }
    }
    __syncthreads();
    if (tid < 256) {
        int ex = wsum[wid] + v - h;
        int gb = 0;
        if (tid < NBUCK && h > 0) gb = atomicAdd(ccur + tid, h);
        exoff[tid] = ex;
        lcur[tid]  = ex;
        gbase[tid] = gb;
    }
    __syncthreads();
    #pragma unroll
    for (int j = 0; j < EPT; j++) {
        if (bk[j] >= 0) {
            int l = atomicAdd(&lcur[bk[j]], 1);
            stage[l]  = pk[j];
            stageB[l] = (unsigned char)bk[j];
        }
    }
    __syncthreads();
    for (int i = tid; i < ec; i += PTHR) {
        int b = stageB[i];
        arena[(size_t)b * CAP + gbase[b] + (i - exoff[b])] = stage[i];
    }
}

// One 1024-thr block per coarse bucket. R20: counting sort over 4096 bins
// key = (fine_dst << 3) | (src >> SSH)  -> per-row edge lists ordered by
// source chunk (L2 temporal locality for the gathers). off[] = start of a
// row's first bin; ssrc gets 17-bit src as before.
__global__ __launch_bounds__(1024) void csr_fine(const int* __restrict__ arena,
                                                 const int* __restrict__ ccur,
                                                 int* __restrict__ off,
                                                 int* __restrict__ ssrc,
                                                 int N, int E, int NBUCK) {
    __shared__ int part[256];
    __shared__ int cnt[NBIN];
    __shared__ int cur[NBIN];
    __shared__ int wpre[16];
    const int b = blockIdx.x;
    const int node0 = b << CSHIFT;
    const int tid = threadIdx.x;
    const int lane = tid & 63, wid = tid >> 6;

    // exclusive prefix of ccur over buckets -> cbeg
    if (tid < 256) part[tid] = (tid < NBUCK) ? ccur[tid] : 0;
    __syncthreads();
    for (int d = 1; d < 256; d <<= 1) {
        int v = 0;
        if (tid < 256 && tid >= d) v = part[tid - d];
        __syncthreads();
        if (tid < 256 && tid >= d) part[tid] += v;
        __syncthreads();
    }
    const int cbeg = (b > 0) ? part[b - 1] : 0;
    const int ec   = min(ccur[b], CAP);
    if (b == 0 && tid == 0) off[N] = E;

    #pragma unroll
    for (int k = 0; k < NBIN / 1024; k++) cnt[tid + k * 1024] = 0;
    __syncthreads();
    const int* pe = arena + (size_t)b * CAP;
    for (int i = tid; i < ec; i += 1024) {
        int p = pe[i];
        int key = (((p >> 17) & (CNODES - 1)) << 3) | ((p & 0x1FFFF) >> SSH);
        atomicAdd(&cnt[key], 1);
    }
    __syncthreads();

    // scan 4096 bins: 4 serial/thread + shuffle scan over 16 waves
    const int t4 = tid * 4;
    int s0 = cnt[t4], s1 = cnt[t4 + 1], s2 = cnt[t4 + 2], s3 = cnt[t4 + 3];
    int l1 = s0, l2 = s0 + s1, l3 = s0 + s1 + s2;
    int tsum = l3 + s3;
    int v = tsum;
    #pragma unroll
    for (int d = 1; d < 64; d <<= 1) {
        int t = __shfl_up(v, d);
        if (lane >= d) v += t;
    }
    if (lane == 63) wpre[wid] = v;
    __syncthreads();
    if (tid == 0) {
        int s = 0;
        #pragma unroll
        for (int k = 0; k < 16; k++) { int t = wpre[k]; wpre[k] = s; s += t; }
    }
    __syncthreads();
    const int ex0 = wpre[wid] + v - tsum;      // exclusive prefix of bin t4
    cur[t4]     = ex0;
    cur[t4 + 1] = ex0 + l1;
    cur[t4 + 2] = ex0 + l2;
    cur[t4 + 3] = ex0 + l3;
    // bins for fine node f are [f*8, f*8+8); t4 = tid*4 covers 2 node starts
    // when t4%8==0 (k=0) and t4+4... only k where (t4+k)&7==0 is k=0 for even
    // tid*4%8: tid even -> t4%8==0. Write off at each bin with (bin&7)==0.
    {
        int bin = t4;                            // (t4 & 3)==0 always
        if ((bin & 7) == 0) {
            int node = node0 + (bin >> 3);
            if (node < N) off[node] = cbeg + ex0;
        }
        bin = t4 + 4;
        if ((bin & 7) == 0) {                    // t4%8==4 case
            int node = node0 + (bin >> 3);
            if (node < N) off[node] = cbeg + ex0 + l3 + s3 - s3 + 0;  // == ex of bin t4+4
        }
    }
    __syncthreads();
    for (int i = tid; i < ec; i += 1024) {
        int p = pe[i];
        int key = (((p >> 17) & (CNODES - 1)) << 3) | ((p & 0x1FFFF) >> SSH);
        int pos = cbeg + atomicAdd(&cur[key], 1);
        ssrc[pos] = p & 0x1FFFF;
    }
}

// ---------------- wave-local gather: mean of h[src] rows into LDS tile -----
// Wave w gathers ITS OWN rows w*16..w*16+15 (2 passes x 8 rows x 8 lanes).
// (R17 best config: 8-deep batched loads.)
#define ACC8(v)                                    \
    acc[0] += __uint_as_float((v).x << 16);        \
    acc[1] += __uint_as_float((v).x & 0xFFFF0000u);\
    acc[2] += __uint_as_float((v).y << 16);        \
    acc[3] += __uint_as_float((v).y & 0xFFFF0000u);\
    acc[4] += __uint_as_float((v).z << 16);        \
    acc[5] += __uint_as_float((v).z & 0xFFFF0000u);\
    acc[6] += __uint_as_float((v).w << 16);        \
    acc[7] += __uint_as_float((v).w & 0xFFFF0000u);

__device__ __forceinline__ void gather_tile_wave(
    const unsigned short* __restrict__ h, const int* __restrict__ off,
    const int* __restrict__ ssrc, unsigned short* Agg, int rowB, int N,
    int w, int lane)
{
    #pragma unroll
    for (int pass = 0; pass < 2; pass++) {
        int rl = w * 16 + pass * 8 + (lane >> 3);
        int g  = rowB + rl;
        int q  = (lane & 7) * 8;
        uint4 p = make_uint4(0u, 0u, 0u, 0u);
        if (g < N) {
            int beg = off[g], end = off[g + 1];
            float acc[8] = {0.f, 0.f, 0.f, 0.f, 0.f, 0.f, 0.f, 0.f};
            int i = beg;
            for (; i + 8 <= end; i += 8) {       // 8 loads in flight per lane
                uint4 v0 = *(const uint4*)(h + (size_t)ssrc[i]     * 64 + q);
                uint4 v1 = *(const uint4*)(h + (size_t)ssrc[i + 1] * 64 + q);
                uint4 v2 = *(const uint4*)(h + (size_t)ssrc[i + 2] * 64 + q);
                uint4 v3 = *(const uint4*)(h + (size_t)ssrc[i + 3] * 64 + q);
                uint4 v4 = *(const uint4*)(h + (size_t)ssrc[i + 4] * 64 + q);
                uint4 v5 = *(const uint4*)(h + (size_t)ssrc[i + 5] * 64 + q);
                uint4 v6 = *(const uint4*)(h + (size_t)ssrc[i + 6] * 64 + q);
                uint4 v7 = *(const uint4*)(h + (size_t)ssrc[i + 7] * 64 + q);
                ACC8(v0); ACC8(v1); ACC8(v2); ACC8(v3);
                ACC8(v4); ACC8(v5); ACC8(v6); ACC8(v7);
            }
            for (; i + 2 <= end; i += 2) {
                uint4 v0 = *(const uint4*)(h + (size_t)ssrc[i]     * 64 + q);
                uint4 v1 = *(const uint4*)(h + (size_t)ssrc[i + 1] * 64 + q);
                ACC8(v0); ACC8(v1);
            }
            for (; i < end; i++) {
                uint4 v = *(const uint4*)(h + (size_t)ssrc[i] * 64 + q);
                ACC8(v);
            }
            // v_rcp_f32: 2^-22 rel err, absorbed by the bf16 round
            float inv = __builtin_amdgcn_rcpf((float)max(end - beg, 1));
            p.x = (unsigned)f2bf(acc[0]*inv) | ((unsigned)f2bf(acc[1]*inv) << 16);
            p.y = (unsigned)f2bf(acc[2]*inv) | ((unsigned)f2bf(acc[3]*inv) << 16);
            p.z = (unsigned)f2bf(acc[4]*inv) | ((unsigned)f2bf(acc[5]*inv) << 16);
            p.w = (unsigned)f2bf(acc[6]*inv) | ((unsigned)f2bf(acc[7]*inv) << 16);
        }
        *(uint4*)(Agg + rl * 72 + q) = p;
    }
}

// ---------------- fused gather + GEMM1 + sigmoid -> t1 ---------------------
// 128 threads / 32-row tile, grid 3125 (R17 best config).
__global__ __launch_bounds__(128) void aggemm1_k(
    const unsigned short* __restrict__ featbf, const int* __restrict__ off,
    const int* __restrict__ ssrc, const unsigned short* __restrict__ img,
    const float* __restrict__ bias, unsigned short* __restrict__ t1, int N)
{
    __shared__ alignas(16) unsigned short Agg[32 * 72];   // 4.6 KB

    const int tid = threadIdx.x;
    const int rowB = blockIdx.x * 32;
    const int w = tid >> 6, lane = tid & 63;
    const int m = lane & 15, quad = lane >> 4;
    const int row0 = rowB + w * 16;

    gather_tile_wave(featbf, off, ssrc, Agg, rowB, N, w, lane);

    const short8* Wf = (const short8*)(img + W1F_OFF);
    floatx4 acc[4];
    #pragma unroll
    for (int c = 0; c < 4; c++) acc[c] = (floatx4){0.f, 0.f, 0.f, 0.f};
    #pragma unroll
    for (int kk = 0; kk < 2; kk++) {
        short8 a = *(const short8*)(Agg + (w * 16 + m) * 72 + kk * 32 + quad * 8);
        #pragma unroll
        for (int c = 0; c < 4; c++) {
            short8 b = Wf[((c * 2 + kk) * 4 + quad) * 16 + m];
            acc[c] = __builtin_amdgcn_mfma_f32_16x16x32_bf16(a, b, acc[c], 0, 0, 0);
        }
    }
    bool dzr[4];
    int rows[4];
    #pragma unroll
    for (int r = 0; r < 4; r++) {
        rows[r] = row0 + quad * 4 + r;
        dzr[r] = (rows[r] < N) ? (off[rows[r] + 1] == off[rows[r]]) : false;
    }
    #pragma unroll
    for (int c = 0; c < 4; c++) {
        int col = c * 16 + m;
        float bv = bias[col];
        #pragma unroll
        for (int r = 0; r < 4; r++) {
            if (rows[r] < N) {
                float v = dzr[r] ? 0.5f : sigmoidf(acc[c][r] + bv);
                t1[(size_t)rows[r] * 64 + col] = f2bf(v);
            }
        }
    }
}

// ---------------- fused gather + triple-GEMM -> out ------------------------
// 128 threads / 32-row tile; LDS: T2[0,2304) | Agg/H3h[2304,4608) shorts.
// Every LDS row is touched only by its owning wave -> no __syncthreads.
__global__ __launch_bounds__(128) void aggep3_k(
    const unsigned short* __restrict__ t1, const int* __restrict__ off,
    const int* __restrict__ ssrc, const unsigned short* __restrict__ img,
    const float* __restrict__ b2, const float* __restrict__ b3,
    const float* __restrict__ b4, float* __restrict__ out, int N)
{
    __shared__ alignas(16) unsigned short SM[4608];   // 9.2 KB
    unsigned short* T2  = SM;            // 32 x 72
    unsigned short* Agg = SM + 2304;     // 32 x 72 (dead after phase 0)
    unsigned short* H3h = SM + 2304;     // aliases Agg

    const int tid = threadIdx.x;
    const int rowB = blockIdx.x * 32;
    const int w = tid >> 6, lane = tid & 63;
    const int m = lane & 15, quad = lane >> 4;
    const int row0 = rowB + w * 16;

    gather_tile_wave(t1, off, ssrc, Agg, rowB, N, w, lane);

    // ---- phase 0: T2 = sigmoid(Agg @ W2 + b2) ----
    {
        const short8* Wf = (const short8*)(img + W2F_OFF);
        floatx4 acc[4];
        #pragma unroll
        for (int c = 0; c < 4; c++) acc[c] = (floatx4){0.f, 0.f, 0.f, 0.f};
        #pragma unroll
        for (int kk = 0; kk < 2; kk++) {
            short8 a = *(const short8*)(Agg + (w * 16 + m) * 72 + kk * 32 + quad * 8);
            #pragma unroll
            for (int c = 0; c < 4; c++) {
                short8 b = Wf[((c * 2 + kk) * 4 + quad) * 16 + m];
                acc[c] = __builtin_amdgcn_mfma_f32_16x16x32_bf16(a, b, acc[c], 0, 0, 0);
            }
        }
        bool dzr[4];
        #pragma unroll
        for (int r = 0; r < 4; r++) {
            int row = row0 + quad * 4 + r;
            dzr[r] = (row < N) ? (off[row + 1] == off[row]) : false;
        }
        #pragma unroll
        for (int c = 0; c < 4; c++) {
            int col = c * 16 + m;
            float bv = b2[col];
            #pragma unroll
            for (int r = 0; r < 4; r++) {
                int rl = w * 16 + quad * 4 + r;
                float v = dzr[r] ? 0.5f : sigmoidf(acc[c][r] + bv);
                T2[rl * 72 + col] = f2bf(v);
            }
        }
    }

    // ---- phases 1&2 split-K: per half, H3h = relu(T2@W3half+b3half),
    //      then acc2 += H3h @ W4[khalf] ----
    floatx4 acc2[3];
    #pragma unroll
    for (int c = 0; c < 3; c++) acc2[c] = (floatx4){0.f, 0.f, 0.f, 0.f};
    const short8* Wf3 = (const short8*)(img + W3F_OFF);
    const short8* Wf4 = (const short8*)(img + W4F_OFF);

    #pragma unroll
    for (int half = 0; half < 2; half++) {
        floatx4 acc[4];
        #pragma unroll
        for (int c = 0; c < 4; c++) acc[c] = (floatx4){0.f, 0.f, 0.f, 0.f};
        #pragma unroll
        for (int kk = 0; kk < 2; kk++) {
            short8 a = *(const short8*)(T2 + (w * 16 + m) * 72 + kk * 32 + quad * 8);
            #pragma unroll
            for (int c = 0; c < 4; c++) {
                short8 b = Wf3[(((half * 4 + c) * 2 + kk) * 4 + quad) * 16 + m];
                acc[c] = __builtin_amdgcn_mfma_f32_16x16x32_bf16(a, b, acc[c], 0, 0, 0);
            }
        }
        #pragma unroll
        for (int c = 0; c < 4; c++) {
            int col = c * 16 + m;
            float bv = b3[half * 64 + col];
            #pragma unroll
            for (int r = 0; r < 4; r++) {
                int rl = w * 16 + quad * 4 + r;
                H3h[rl * 72 + col] = f2bf(fmaxf(acc[c][r] + bv, 0.f));
            }
        }
        #pragma unroll
        for (int kk2 = 0; kk2 < 2; kk2++) {
            short8 a = *(const short8*)(H3h + (w * 16 + m) * 72 + kk2 * 32 + quad * 8);
            #pragma unroll
            for (int c = 0; c < 3; c++) {
                short8 b = Wf4[((c * 4 + half * 2 + kk2) * 4 + quad) * 16 + m];
                acc2[c] = __builtin_amdgcn_mfma_f32_16x16x32_bf16(a, b, acc2[c], 0, 0, 0);
            }
        }
    }

    // ---- store out = acc2 + b4 ----
    #pragma unroll
    for (int c = 0; c < 3; c++) {
        int col = c * 16 + m;
        if (col < 40) {
            float bv = b4[col];
            #pragma unroll
            for (int r = 0; r < 4; r++) {
                int row = row0 + quad * 4 + r;
                if (row < N) out[(size_t)row * 40 + col] = acc2[c][r] + bv;
            }
        }
    }
}

extern "C" void kernel_launch(void* const* d_in, const int* in_sizes, int n_in,
                              void* d_out, int out_size, void* d_ws, size_t ws_size,
                              hipStream_t stream)
{
    const float* feat = (const float*)d_in[0];
    const int*   eidx = (const int*)d_in[1];
    const float* W1 = (const float*)d_in[2];
    const float* b1 = (const float*)d_in[3];
    const float* W2 = (const float*)d_in[4];
    const float* b2 = (const float*)d_in[5];
    const float* W3 = (const float*)d_in[6];
    const float* b3 = (const float*)d_in[7];
    const float* W4 = (const float*)d_in[8];
    const float* b4 = (const float*)d_in[9];

    const int N = in_sizes[0] / 64;
    const int E = in_sizes[1] / 2;
    const int* src = eidx;
    const int* dst = eidx + E;

    const int NBUCK = (N + CNODES - 1) / CNODES;   // 196

    unsigned short* featbf = (unsigned short*)d_ws;            // N*64 bf16
    unsigned short* t1     = featbf + (size_t)N * 64;          // N*64 bf16
    unsigned short* img    = t1     + (size_t)N * 64;          // WIMG_TOT
    int*   off   = (int*)(img + WIMG_TOT);                     // N+1
    int*   ccur  = off + (N + 1);                              // NBUCK
    int*   ssrc  = ccur + NBUCK;                               // E
    int*   arena = ssrc + E;                                   // NBUCK*CAP
    float* out   = (float*)d_out;

    hipMemsetAsync(ccur, 0, (size_t)NBUCK * sizeof(int), stream);

    const int gP  = (E + EPB - 1) / EPB;
    const int g32 = (N + 31) / 32;
    const int n8  = N * 64 / 8;
    const int gPC = (n8 + WIMG_TOT + PTHR - 1) / PTHR;

    // CSR partition + prep (merged, 512thr), then per-bucket chunk-ordered
    // counting sort (R20)
    part_prep_k<<<gP + gPC, dim3(PTHR), 0, stream>>>(src, dst, ccur, arena, E,
                                                     NBUCK, gP, feat, featbf,
                                                     W1, W2, W3, W4, img, n8);
    csr_fine<<<NBUCK, dim3(1024), 0, stream>>>(arena, ccur, off, ssrc, N, E, NBUCK);

    // t1 = sigmoid(mean(featbf[src]) @ W1 + b1)   [fused, 0 barriers]
    aggemm1_k<<<g32, dim3(128), 0, stream>>>(featbf, off, ssrc, img, b1, t1, N);
    // out = relu(sigmoid(mean(t1[src])@W2+b2)@W3+b3)@W4 + b4  [fused, 0 barriers]
    aggep3_k<<<g32, dim3(128), 0, stream>>>(t1, off, ssrc, img, b2, b3, b4, out, N);
}

// Round 8
// 211.704 us; speedup vs baseline: 1.0658x; 1.0130x over previous
//
#include <hip/hip_runtime.h>

// HGCN on MI355X. logmap0(expmap0(v)) == v here, so the model reduces to:
//   t1 = sigmoid(segmean(feat@W1+b1)); t2 = sigmoid(segmean(t1@W2+b2))
//   out = relu(t2@W3+b3)@W4 + b4     (segmean commutes with the linear map;
//   deg-0 nodes: segmean = 0 -> value 0.5 exactly, handled via dz check)
// R1-R13: see session journal (atomic wall -> CSR; coarse buckets; bf16
//   gather rows; frag-packed weight image; wave-local zero-barrier MLP).
// R14: baseline re-anchor, 229.4us. Gathers latency-bound (occ ~30%).
// R15: FAILED (1356us). LDS float atomicAdd = CAS loop, not ds_add_f32.
// R16: FAILED (240us). Fine buckets @ part_prep -> write-amp; sort once.
// R17: WIN (219us). csr_fine@1024thr; gathers 128thr/32-row; aggep3 59->48.
// R18: NET LOSS (225.6). part_prep@512 won ~13us (kept); 16-deep single
//   chain lost (regalloc caps in-flight ~8).
// R19: NULL (220.4). occ up, dur flat: gathers not concurrency-bound.
// R20: NULL on mechanism (214.5 total, aggep3 FETCH/dur UNCHANGED). Chunk
//   sort can't work: ~2 edges/chunk/row + no cross-block time alignment.
//   4 configs converge at ~2.0-2.1TB/s fabric = random-access wall; only
//   traffic reduction moves the gathers.
// R21: preprocessing CU-coverage round. CSHIFT 9->8: csr_fine 196->391
//   blocks (every CU busy), bins 4096->256 (revert R20 chunk keys, LDS
//   33KB->2KB); shuffle scans everywhere; stageB -> ushort. Cost: 42B arena
//   runs => mild write-amp in part_prep (+~4us). Gathers untouched.
//   Predicted total 214.5 -> ~195-205; aggep3 unchanged 47.5/79MB.

constexpr int CSHIFT = 8;               // 256 nodes per coarse bucket (R21)
constexpr int CNODES = 1 << CSHIFT;
constexpr int EPB    = 4096;            // edges per partition block
constexpr int PTHR   = 512;             // partition block threads
constexpr int EPT    = EPB / PTHR;      // 8 edges/thread
constexpr int CAP    = 6144;            // arena cap/bucket (mean 4082, +32s)

// frag-packed bf16 weight image (shorts). Fragment = 16 lanes x 8 shorts =
// 128 shorts; flat idx = (((c*KK + kk)*4 + quad)*16 + m)*8 + j.
constexpr int W1F_OFF = 0;              // 4x2x4 frags  = 4096 shorts
constexpr int W2F_OFF = 4096;           // 4096
constexpr int W3F_OFF = 8192;           // 8x2x4 frags  = 8192
constexpr int W4F_OFF = 16384;          // 3x4x4 frags  = 6144 (cols padded 48)
constexpr int WIMG_TOT = 22528;

typedef __attribute__((ext_vector_type(8))) short short8;   // 8 bf16
typedef __attribute__((ext_vector_type(4))) float floatx4;  // MFMA acc

__device__ __forceinline__ float sigmoidf(float x) {
    return 1.0f / (1.0f + __expf(-x));
}
__device__ __forceinline__ unsigned short f2bf(float f) {   // RNE f32->bf16
    unsigned int u = __float_as_uint(f);
    u = (u + 0x7FFFu + ((u >> 16) & 1u)) >> 16;
    return (unsigned short)u;
}

// ---------------- CSR partition + one-time prep (merged launch) ------------
// Blocks [0,gP): radix-partition edges into per-bucket arena regions
//   (391 buckets now -> 512-wide hist, 8-wave shuffle scan).
// Blocks [gP,..): feat fp32->bf16 cast + frag-packed weight image build.
__global__ __launch_bounds__(512) void part_prep_k(
    const int* __restrict__ src, const int* __restrict__ dst,
    int* __restrict__ ccur, int* __restrict__ arena, int E, int NBUCK, int gP,
    const float* __restrict__ feat, unsigned short* __restrict__ featbf,
    const float* __restrict__ W1, const float* __restrict__ W2,
    const float* __restrict__ W3, const float* __restrict__ W4,
    unsigned short* __restrict__ img, int n8)
{
    __shared__ int  hist[512];
    __shared__ int  exoff[512];
    __shared__ int  lcur[512];
    __shared__ int  gbase[512];
    __shared__ int  wsum[8];
    __shared__ int  stage[EPB];
    __shared__ unsigned short stageS[EPB];   // bucket id (up to 390)

    const int tid = threadIdx.x;

    if ((int)blockIdx.x >= gP) {
        // ---- prep path ----
        int i = ((int)blockIdx.x - gP) * PTHR + tid;
        if (i < n8) {
            const float4* p = (const float4*)feat + (size_t)i * 2;
            float4 a = p[0], b = p[1];
            uint4 o;
            o.x = (unsigned)f2bf(a.x) | ((unsigned)f2bf(a.y) << 16);
            o.y = (unsigned)f2bf(a.z) | ((unsigned)f2bf(a.w) << 16);
            o.z = (unsigned)f2bf(b.x) | ((unsigned)f2bf(b.y) << 16);
            o.w = (unsigned)f2bf(b.z) | ((unsigned)f2bf(b.w) << 16);
            ((uint4*)featbf)[i] = o;
            return;
        }
        int t = i - n8;
        if (t >= WIMG_TOT) return;
        float v = 0.f;
        int s = t;
        if (s < W2F_OFF) {                       // W1 [64x64]
            int j = s & 7, m = (s >> 3) & 15, q = (s >> 7) & 3, kk = (s >> 9) & 1, c = s >> 10;
            v = W1[(kk * 32 + q * 8 + j) * 64 + c * 16 + m];
        } else if (s < W3F_OFF) {                // W2 [64x64]
            s -= W2F_OFF;
            int j = s & 7, m = (s >> 3) & 15, q = (s >> 7) & 3, kk = (s >> 9) & 1, c = s >> 10;
            v = W2[(kk * 32 + q * 8 + j) * 64 + c * 16 + m];
        } else if (s < W4F_OFF) {                // W3 [64x128]
            s -= W3F_OFF;
            int j = s & 7, m = (s >> 3) & 15, q = (s >> 7) & 3, kk = (s >> 9) & 1, c = s >> 10;
            v = W3[(kk * 32 + q * 8 + j) * 128 + c * 16 + m];
        } else {                                 // W4 [128x40], cols padded 48
            s -= W4F_OFF;
            int j = s & 7, m = (s >> 3) & 15, q = (s >> 7) & 3, kk = (s >> 9) & 3, c = s >> 11;
            int n = c * 16 + m;
            if (n < 40) v = W4[(kk * 32 + q * 8 + j) * 40 + n];
        }
        img[t] = f2bf(v);
        return;
    }

    // ---- partition path (512 threads, 512-entry hist) ----
    const int e0  = blockIdx.x * EPB;
    const int ec  = min(EPB, E - e0);
    const int lane = tid & 63, wid = tid >> 6;

    int pk[EPT], bk[EPT];
    hist[tid] = 0;
    __syncthreads();
    #pragma unroll
    for (int j = 0; j < EPT; j++) {
        int idx = tid + j * PTHR;
        if (idx < ec) {
            int s = src[e0 + idx];
            int d = dst[e0 + idx];
            bk[j] = d >> CSHIFT;
            pk[j] = s | ((d & (CNODES - 1)) << 17);
            atomicAdd(&hist[bk[j]], 1);
        } else bk[j] = -1;
    }
    __syncthreads();
    // shuffle scan of hist[512] over all 8 waves
    int h = hist[tid];
    int v = h;
    #pragma unroll
    for (int d = 1; d < 64; d <<= 1) {
        int t = __shfl_up(v, d);
        if (lane >= d) v += t;
    }
    if (lane == 63) wsum[wid] = v;
    __syncthreads();
    if (tid == 0) {
        int s = 0;
        #pragma unroll
        for (int k = 0; k < 8; k++) { int t = wsum[k]; wsum[k] = s; s += t; }
    }
    __syncthreads();
    {
        int ex = wsum[wid] + v - h;
        int gb = 0;
        if (tid < NBUCK && h > 0) gb = atomicAdd(ccur + tid, h);
        exoff[tid] = ex;
        lcur[tid]  = ex;
        gbase[tid] = gb;
    }
    __syncthreads();
    #pragma unroll
    for (int j = 0; j < EPT; j++) {
        if (bk[j] >= 0) {
            int l = atomicAdd(&lcur[bk[j]], 1);
            stage[l]  = pk[j];
            stageS[l] = (unsigned short)bk[j];
        }
    }
    __syncthreads();
    for (int i = tid; i < ec; i += PTHR) {
        int b = stageS[i];
        arena[(size_t)b * CAP + gbase[b] + (i - exoff[b])] = stage[i];
    }
}

// One 1024-thr block per 256-node bucket (391 blocks = 1.53/CU, every CU
// busy). Shuffle-scan cross-bucket prefix -> cbeg; 256-bin counting sort
// -> off/ssrc.
__global__ __launch_bounds__(1024) void csr_fine(const int* __restrict__ arena,
                                                 const int* __restrict__ ccur,
                                                 int* __restrict__ off,
                                                 int* __restrict__ ssrc,
                                                 int N, int E, int NBUCK) {
    __shared__ int part[512];
    __shared__ int cnt[CNODES];
    __shared__ int cur[CNODES];
    __shared__ int wpre[8];
    __shared__ int wpre2[4];
    const int b = blockIdx.x;
    const int node0 = b << CSHIFT;
    const int tid = threadIdx.x;
    const int lane = tid & 63, wid = tid >> 6;

    // cross-bucket inclusive scan of ccur[NBUCK<=512] via waves 0-7 shuffle
    int c0 = 0, v0 = 0;
    if (tid < 512) {
        c0 = (tid < NBUCK) ? ccur[tid] : 0;
        v0 = c0;
        #pragma unroll
        for (int d = 1; d < 64; d <<= 1) {
            int t = __shfl_up(v0, d);
            if (lane >= d) v0 += t;
        }
        if (lane == 63) wpre[wid] = v0;
    }
    __syncthreads();
    if (tid == 0) {
        int s = 0;
        #pragma unroll
        for (int k = 0; k < 8; k++) { int t = wpre[k]; wpre[k] = s; s += t; }
    }
    __syncthreads();
    if (tid < 512) part[tid] = wpre[wid] + v0;   // inclusive prefix
    __syncthreads();
    const int cbeg = (b > 0) ? part[b - 1] : 0;
    const int ec   = min(ccur[b], CAP);
    if (b == 0 && tid == 0) off[N] = E;

    if (tid < CNODES) cnt[tid] = 0;
    __syncthreads();
    const int* pe = arena + (size_t)b * CAP;
    for (int i = tid; i < ec; i += 1024)
        atomicAdd(&cnt[(pe[i] >> 17) & (CNODES - 1)], 1);
    __syncthreads();

    // scan cnt[256] on waves 0-3
    int c = 0, v = 0;
    if (tid < CNODES) {
        c = cnt[tid];
        v = c;
        #pragma unroll
        for (int d = 1; d < 64; d <<= 1) {
            int t = __shfl_up(v, d);
            if (lane >= d) v += t;
        }
        if (lane == 63) wpre2[wid] = v;
    }
    __syncthreads();
    if (tid == 0) {
        int s = 0;
        #pragma unroll
        for (int k = 0; k < CNODES / 64; k++) { int t = wpre2[k]; wpre2[k] = s; s += t; }
    }
    __syncthreads();
    if (tid < CNODES) {
        int ex = wpre2[wid] + v - c;             // exclusive prefix in bucket
        cur[tid] = ex;
        int node = node0 + tid;
        if (node < N) off[node] = cbeg + ex;
    }
    __syncthreads();
    for (int i = tid; i < ec; i += 1024) {
        int p = pe[i];
        int pos = cbeg + atomicAdd(&cur[(p >> 17) & (CNODES - 1)], 1);
        ssrc[pos] = p & 0x1FFFF;
    }
}

// ---------------- wave-local gather: mean of h[src] rows into LDS tile -----
// Wave w gathers ITS OWN rows w*16..w*16+15 (2 passes x 8 rows x 8 lanes).
// (R17/R20 proven config: 8-deep batched loads.)
#define ACC8(v)                                    \
    acc[0] += __uint_as_float((v).x << 16);        \
    acc[1] += __uint_as_float((v).x & 0xFFFF0000u);\
    acc[2] += __uint_as_float((v).y << 16);        \
    acc[3] += __uint_as_float((v).y & 0xFFFF0000u);\
    acc[4] += __uint_as_float((v).z << 16);        \
    acc[5] += __uint_as_float((v).z & 0xFFFF0000u);\
    acc[6] += __uint_as_float((v).w << 16);        \
    acc[7] += __uint_as_float((v).w & 0xFFFF0000u);

__device__ __forceinline__ void gather_tile_wave(
    const unsigned short* __restrict__ h, const int* __restrict__ off,
    const int* __restrict__ ssrc, unsigned short* Agg, int rowB, int N,
    int w, int lane)
{
    #pragma unroll
    for (int pass = 0; pass < 2; pass++) {
        int rl = w * 16 + pass * 8 + (lane >> 3);
        int g  = rowB + rl;
        int q  = (lane & 7) * 8;
        uint4 p = make_uint4(0u, 0u, 0u, 0u);
        if (g < N) {
            int beg = off[g], end = off[g + 1];
            float acc[8] = {0.f, 0.f, 0.f, 0.f, 0.f, 0.f, 0.f, 0.f};
            int i = beg;
            for (; i + 8 <= end; i += 8) {       // 8 loads in flight per lane
                uint4 v0 = *(const uint4*)(h + (size_t)ssrc[i]     * 64 + q);
                uint4 v1 = *(const uint4*)(h + (size_t)ssrc[i + 1] * 64 + q);
                uint4 v2 = *(const uint4*)(h + (size_t)ssrc[i + 2] * 64 + q);
                uint4 v3 = *(const uint4*)(h + (size_t)ssrc[i + 3] * 64 + q);
                uint4 v4 = *(const uint4*)(h + (size_t)ssrc[i + 4] * 64 + q);
                uint4 v5 = *(const uint4*)(h + (size_t)ssrc[i + 5] * 64 + q);
                uint4 v6 = *(const uint4*)(h + (size_t)ssrc[i + 6] * 64 + q);
                uint4 v7 = *(const uint4*)(h + (size_t)ssrc[i + 7] * 64 + q);
                ACC8(v0); ACC8(v1); ACC8(v2); ACC8(v3);
                ACC8(v4); ACC8(v5); ACC8(v6); ACC8(v7);
            }
            for (; i + 2 <= end; i += 2) {
                uint4 v0 = *(const uint4*)(h + (size_t)ssrc[i]     * 64 + q);
                uint4 v1 = *(const uint4*)(h + (size_t)ssrc[i + 1] * 64 + q);
                ACC8(v0); ACC8(v1);
            }
            for (; i < end; i++) {
                uint4 v = *(const uint4*)(h + (size_t)ssrc[i] * 64 + q);
                ACC8(v);
            }
            // v_rcp_f32: 2^-22 rel err, absorbed by the bf16 round
            float inv = __builtin_amdgcn_rcpf((float)max(end - beg, 1));
            p.x = (unsigned)f2bf(acc[0]*inv) | ((unsigned)f2bf(acc[1]*inv) << 16);
            p.y = (unsigned)f2bf(acc[2]*inv) | ((unsigned)f2bf(acc[3]*inv) << 16);
            p.z = (unsigned)f2bf(acc[4]*inv) | ((unsigned)f2bf(acc[5]*inv) << 16);
            p.w = (unsigned)f2bf(acc[6]*inv) | ((unsigned)f2bf(acc[7]*inv) << 16);
        }
        *(uint4*)(Agg + rl * 72 + q) = p;
    }
}

// ---------------- fused gather + GEMM1 + sigmoid -> t1 ---------------------
// 128 threads / 32-row tile, grid 3125 (R17 best config).
__global__ __launch_bounds__(128) void aggemm1_k(
    const unsigned short* __restrict__ featbf, const int* __restrict__ off,
    const int* __restrict__ ssrc, const unsigned short* __restrict__ img,
    const float* __restrict__ bias, unsigned short* __restrict__ t1, int N)
{
    __shared__ alignas(16) unsigned short Agg[32 * 72];   // 4.6 KB

    const int tid = threadIdx.x;
    const int rowB = blockIdx.x * 32;
    const int w = tid >> 6, lane = tid & 63;
    const int m = lane & 15, quad = lane >> 4;
    const int row0 = rowB + w * 16;

    gather_tile_wave(featbf, off, ssrc, Agg, rowB, N, w, lane);

    const short8* Wf = (const short8*)(img + W1F_OFF);
    floatx4 acc[4];
    #pragma unroll
    for (int c = 0; c < 4; c++) acc[c] = (floatx4){0.f, 0.f, 0.f, 0.f};
    #pragma unroll
    for (int kk = 0; kk < 2; kk++) {
        short8 a = *(const short8*)(Agg + (w * 16 + m) * 72 + kk * 32 + quad * 8);
        #pragma unroll
        for (int c = 0; c < 4; c++) {
            short8 b = Wf[((c * 2 + kk) * 4 + quad) * 16 + m];
            acc[c] = __builtin_amdgcn_mfma_f32_16x16x32_bf16(a, b, acc[c], 0, 0, 0);
        }
    }
    bool dzr[4];
    int rows[4];
    #pragma unroll
    for (int r = 0; r < 4; r++) {
        rows[r] = row0 + quad * 4 + r;
        dzr[r] = (rows[r] < N) ? (off[rows[r] + 1] == off[rows[r]]) : false;
    }
    #pragma unroll
    for (int c = 0; c < 4; c++) {
        int col = c * 16 + m;
        float bv = bias[col];
        #pragma unroll
        for (int r = 0; r < 4; r++) {
            if (rows[r] < N) {
                float v = dzr[r] ? 0.5f : sigmoidf(acc[c][r] + bv);
                t1[(size_t)rows[r] * 64 + col] = f2bf(v);
            }
        }
    }
}

// ---------------- fused gather + triple-GEMM -> out ------------------------
// 128 threads / 32-row tile; LDS: T2[0,2304) | Agg/H3h[2304,4608) shorts.
// Every LDS row is touched only by its owning wave -> no __syncthreads.
__global__ __launch_bounds__(128) void aggep3_k(
    const unsigned short* __restrict__ t1, const int* __restrict__ off,
    const int* __restrict__ ssrc, const unsigned short* __restrict__ img,
    const float* __restrict__ b2, const float* __restrict__ b3,
    const float* __restrict__ b4, float* __restrict__ out, int N)
{
    __shared__ alignas(16) unsigned short SM[4608];   // 9.2 KB
    unsigned short* T2  = SM;            // 32 x 72
    unsigned short* Agg = SM + 2304;     // 32 x 72 (dead after phase 0)
    unsigned short* H3h = SM + 2304;     // aliases Agg

    const int tid = threadIdx.x;
    const int rowB = blockIdx.x * 32;
    const int w = tid >> 6, lane = tid & 63;
    const int m = lane & 15, quad = lane >> 4;
    const int row0 = rowB + w * 16;

    gather_tile_wave(t1, off, ssrc, Agg, rowB, N, w, lane);

    // ---- phase 0: T2 = sigmoid(Agg @ W2 + b2) ----
    {
        const short8* Wf = (const short8*)(img + W2F_OFF);
        floatx4 acc[4];
        #pragma unroll
        for (int c = 0; c < 4; c++) acc[c] = (floatx4){0.f, 0.f, 0.f, 0.f};
        #pragma unroll
        for (int kk = 0; kk < 2; kk++) {
            short8 a = *(const short8*)(Agg + (w * 16 + m) * 72 + kk * 32 + quad * 8);
            #pragma unroll
            for (int c = 0; c < 4; c++) {
                short8 b = Wf[((c * 2 + kk) * 4 + quad) * 16 + m];
                acc[c] = __builtin_amdgcn_mfma_f32_16x16x32_bf16(a, b, acc[c], 0, 0, 0);
            }
        }
        bool dzr[4];
        #pragma unroll
        for (int r = 0; r < 4; r++) {
            int row = row0 + quad * 4 + r;
            dzr[r] = (row < N) ? (off[row + 1] == off[row]) : false;
        }
        #pragma unroll
        for (int c = 0; c < 4; c++) {
            int col = c * 16 + m;
            float bv = b2[col];
            #pragma unroll
            for (int r = 0; r < 4; r++) {
                int rl = w * 16 + quad * 4 + r;
                float v = dzr[r] ? 0.5f : sigmoidf(acc[c][r] + bv);
                T2[rl * 72 + col] = f2bf(v);
            }
        }
    }

    // ---- phases 1&2 split-K: per half, H3h = relu(T2@W3half+b3half),
    //      then acc2 += H3h @ W4[khalf] ----
    floatx4 acc2[3];
    #pragma unroll
    for (int c = 0; c < 3; c++) acc2[c] = (floatx4){0.f, 0.f, 0.f, 0.f};
    const short8* Wf3 = (const short8*)(img + W3F_OFF);
    const short8* Wf4 = (const short8*)(img + W4F_OFF);

    #pragma unroll
    for (int half = 0; half < 2; half++) {
        floatx4 acc[4];
        #pragma unroll
        for (int c = 0; c < 4; c++) acc[c] = (floatx4){0.f, 0.f, 0.f, 0.f};
        #pragma unroll
        for (int kk = 0; kk < 2; kk++) {
            short8 a = *(const short8*)(T2 + (w * 16 + m) * 72 + kk * 32 + quad * 8);
            #pragma unroll
            for (int c = 0; c < 4; c++) {
                short8 b = Wf3[(((half * 4 + c) * 2 + kk) * 4 + quad) * 16 + m];
                acc[c] = __builtin_amdgcn_mfma_f32_16x16x32_bf16(a, b, acc[c], 0, 0, 0);
            }
        }
        #pragma unroll
        for (int c = 0; c < 4; c++) {
            int col = c * 16 + m;
            float bv = b3[half * 64 + col];
            #pragma unroll
            for (int r = 0; r < 4; r++) {
                int rl = w * 16 + quad * 4 + r;
                H3h[rl * 72 + col] = f2bf(fmaxf(acc[c][r] + bv, 0.f));
            }
        }
        #pragma unroll
        for (int kk2 = 0; kk2 < 2; kk2++) {
            short8 a = *(const short8*)(H3h + (w * 16 + m) * 72 + kk2 * 32 + quad * 8);
            #pragma unroll
            for (int c = 0; c < 3; c++) {
                short8 b = Wf4[((c * 4 + half * 2 + kk2) * 4 + quad) * 16 + m];
                acc2[c] = __builtin_amdgcn_mfma_f32_16x16x32_bf16(a, b, acc2[c], 0, 0, 0);
            }
        }
    }

    // ---- store out = acc2 + b4 ----
    #pragma unroll
    for (int c = 0; c < 3; c++) {
        int col = c * 16 + m;
        if (col < 40) {
            float bv = b4[col];
            #pragma unroll
            for (int r = 0; r < 4; r++) {
                int row = row0 + quad * 4 + r;
                if (row < N) out[(size_t)row * 40 + col] = acc2[c][r] + bv;
            }
        }
    }
}

extern "C" void kernel_launch(void* const* d_in, const int* in_sizes, int n_in,
                              void* d_out, int out_size, void* d_ws, size_t ws_size,
                              hipStream_t stream)
{
    const float* feat = (const float*)d_in[0];
    const int*   eidx = (const int*)d_in[1];
    const float* W1 = (const float*)d_in[2];
    const float* b1 = (const float*)d_in[3];
    const float* W2 = (const float*)d_in[4];
    const float* b2 = (const float*)d_in[5];
    const float* W3 = (const float*)d_in[6];
    const float* b3 = (const float*)d_in[7];
    const float* W4 = (const float*)d_in[8];
    const float* b4 = (const float*)d_in[9];

    const int N = in_sizes[0] / 64;
    const int E = in_sizes[1] / 2;
    const int* src = eidx;
    const int* dst = eidx + E;

    const int NBUCK = (N + CNODES - 1) / CNODES;   // 391

    unsigned short* featbf = (unsigned short*)d_ws;            // N*64 bf16
    unsigned short* t1     = featbf + (size_t)N * 64;          // N*64 bf16
    unsigned short* img    = t1     + (size_t)N * 64;          // WIMG_TOT
    int*   off   = (int*)(img + WIMG_TOT);                     // N+1
    int*   ccur  = off + (N + 1);                              // NBUCK
    int*   ssrc  = ccur + NBUCK;                               // E
    int*   arena = ssrc + E;                                   // NBUCK*CAP
    float* out   = (float*)d_out;

    hipMemsetAsync(ccur, 0, (size_t)NBUCK * sizeof(int), stream);

    const int gP  = (E + EPB - 1) / EPB;
    const int g32 = (N + 31) / 32;
    const int n8  = N * 64 / 8;
    const int gPC = (n8 + WIMG_TOT + PTHR - 1) / PTHR;

    // CSR partition + prep (merged, 512thr), then per-bucket counting sort
    // (391 blocks of 1024thr = 1.53/CU, R21)
    part_prep_k<<<gP + gPC, dim3(PTHR), 0, stream>>>(src, dst, ccur, arena, E,
                                                     NBUCK, gP, feat, featbf,
                                                     W1, W2, W3, W4, img, n8);
    csr_fine<<<NBUCK, dim3(1024), 0, stream>>>(arena, ccur, off, ssrc, N, E, NBUCK);

    // t1 = sigmoid(mean(featbf[src]) @ W1 + b1)   [fused, 0 barriers]
    aggemm1_k<<<g32, dim3(128), 0, stream>>>(featbf, off, ssrc, img, b1, t1, N);
    // out = relu(sigmoid(mean(t1[src])@W2+b2)@W3+b3)@W4 + b4  [fused, 0 barriers]
    aggep3_k<<<g32, dim3(128), 0, stream>>>(t1, off, ssrc, img, b2, b3, b4, out, N);
}